// Round 1
// baseline (444.454 us; speedup 1.0000x reference)
//
#include <hip/hip_runtime.h>
#include <hip/hip_bf16.h>
#include <math.h>

#define NN   1024
#define GG   16
#define DGD  64
#define CLS  80

// ---------------------------------------------------------------------------
// Kernel 1: q = roi@Wq + bq ; k = roi@Wk + bk   (blockIdx.z selects q/k)
// BM=BN=64, BK=32, 256 threads, 4x4 per thread.
// ---------------------------------------------------------------------------
__global__ __launch_bounds__(256) void gemm_qk_k(
    const float* __restrict__ A,
    const float* __restrict__ W0, const float* __restrict__ b0,
    const float* __restrict__ W1, const float* __restrict__ b1,
    float* __restrict__ C0, float* __restrict__ C1)
{
  const float* W    = blockIdx.z ? W1 : W0;
  const float* bias = blockIdx.z ? b1 : b0;
  float*       C    = blockIdx.z ? C1 : C0;
  const int j0 = blockIdx.x * 64;
  const int i0 = blockIdx.y * 64;
  const int t  = threadIdx.x;
  const int tx = t & 15, ty = t >> 4;

  __shared__ float As[64][36];   // pad 36: float4-aligned rows
  __shared__ float Bs[32][68];

  float acc[4][4] = {};

  const int ar = t >> 2, ac = (t & 3) * 8;   // A tile: 64x32
  const int br = t >> 3, bc = (t & 7) * 8;   // B tile: 32x64

  for (int kt = 0; kt < 32; ++kt) {
    const int k0 = kt * 32;
    float4 a0 = *(const float4*)&A[(i0 + ar) * NN + k0 + ac];
    float4 a1 = *(const float4*)&A[(i0 + ar) * NN + k0 + ac + 4];
    float4 w0 = *(const float4*)&W[(k0 + br) * NN + j0 + bc];
    float4 w1 = *(const float4*)&W[(k0 + br) * NN + j0 + bc + 4];
    __syncthreads();
    *(float4*)&As[ar][ac]     = a0;
    *(float4*)&As[ar][ac + 4] = a1;
    *(float4*)&Bs[br][bc]     = w0;
    *(float4*)&Bs[br][bc + 4] = w1;
    __syncthreads();
#pragma unroll
    for (int kk = 0; kk < 32; ++kk) {
      float av[4], bv[4];
#pragma unroll
      for (int im = 0; im < 4; ++im) av[im] = As[ty * 4 + im][kk];
#pragma unroll
      for (int in = 0; in < 4; ++in) bv[in] = Bs[kk][tx * 4 + in];
#pragma unroll
      for (int im = 0; im < 4; ++im)
#pragma unroll
        for (int in = 0; in < 4; ++in)
          acc[im][in] = fmaf(av[im], bv[in], acc[im][in]);
    }
  }
#pragma unroll
  for (int im = 0; im < 4; ++im) {
    const int row = i0 + ty * 4 + im;
    const int col = j0 + tx * 4;
    float4 o;
    o.x = acc[im][0] + bias[col + 0];
    o.y = acc[im][1] + bias[col + 1];
    o.z = acc[im][2] + bias[col + 2];
    o.w = acc[im][3] + bias[col + 3];
    *(float4*)&C[row * NN + col] = o;
  }
}

// ---------------------------------------------------------------------------
// Kernel 2: RW[g][j][kk] = sum_d roi[j][d] * W_conv[g][kk][d]   (NT GEMM)
// grid (16 j-tiles, 16 g), BM=64 (j), BN=64 (kk=DG), BK=32.
// ---------------------------------------------------------------------------
__global__ __launch_bounds__(256) void gemm_rw_k(
    const float* __restrict__ roi, const float* __restrict__ Wc,
    float* __restrict__ RW)
{
  const int g  = blockIdx.y;
  const int j0 = blockIdx.x * 64;
  const int t  = threadIdx.x;
  const int tx = t & 15, ty = t >> 4;

  __shared__ float As[64][33];   // pad 33 (odd): conflict-free strided reads
  __shared__ float Bs[64][33];

  float acc[4][4] = {};
  const int r = t >> 2, c8 = (t & 3) * 8;
  const float* Wg = Wc + (size_t)g * DGD * NN;

  for (int dt = 0; dt < 32; ++dt) {
    const int d0 = dt * 32;
    float4 a0 = *(const float4*)&roi[(j0 + r) * NN + d0 + c8];
    float4 a1 = *(const float4*)&roi[(j0 + r) * NN + d0 + c8 + 4];
    float4 w0 = *(const float4*)&Wg[r * NN + d0 + c8];
    float4 w1 = *(const float4*)&Wg[r * NN + d0 + c8 + 4];
    __syncthreads();
    As[r][c8+0]=a0.x; As[r][c8+1]=a0.y; As[r][c8+2]=a0.z; As[r][c8+3]=a0.w;
    As[r][c8+4]=a1.x; As[r][c8+5]=a1.y; As[r][c8+6]=a1.z; As[r][c8+7]=a1.w;
    Bs[r][c8+0]=w0.x; Bs[r][c8+1]=w0.y; Bs[r][c8+2]=w0.z; Bs[r][c8+3]=w0.w;
    Bs[r][c8+4]=w1.x; Bs[r][c8+5]=w1.y; Bs[r][c8+6]=w1.z; Bs[r][c8+7]=w1.w;
    __syncthreads();
#pragma unroll
    for (int dd = 0; dd < 32; ++dd) {
      float av[4], bv[4];
#pragma unroll
      for (int im = 0; im < 4; ++im) av[im] = As[ty * 4 + im][dd];
#pragma unroll
      for (int in = 0; in < 4; ++in) bv[in] = Bs[tx * 4 + in][dd];
#pragma unroll
      for (int im = 0; im < 4; ++im)
#pragma unroll
        for (int in = 0; in < 4; ++in)
          acc[im][in] = fmaf(av[im], bv[in], acc[im][in]);
    }
  }
#pragma unroll
  for (int im = 0; im < 4; ++im) {
    float4 o; o.x = acc[im][0]; o.y = acc[im][1]; o.z = acc[im][2]; o.w = acc[im][3];
    *(float4*)&RW[(size_t)g * NN * DGD + (j0 + ty * 4 + im) * DGD + tx * 4] = o;
  }
}

// ---------------------------------------------------------------------------
// Kernel 3: paff[i][g][j] = log(max(relu(emb(i,j)@W_pos + b_pos), 1e-6))
// emb: sin/cos positional embedding of the 4 log-ratios.
// ---------------------------------------------------------------------------
__global__ __launch_bounds__(256) void posaff_k(
    const float* __restrict__ bbox, const float* __restrict__ Wp,
    const float* __restrict__ bp, float* __restrict__ paff)
{
  const int i = blockIdx.y;
  const int j = blockIdx.x * 256 + threadIdx.x;

  __shared__ float WpS[1024];
  __shared__ float bpS[16];
  for (int u = threadIdx.x; u < 1024; u += 256) WpS[u] = Wp[u];
  if (threadIdx.x < 16) bpS[threadIdx.x] = bp[threadIdx.x];
  __syncthreads();

  const float xi0 = bbox[i*4+0], yi0 = bbox[i*4+1], xi1 = bbox[i*4+2], yi1 = bbox[i*4+3];
  const float wi = xi1 - xi0 + 1.0f, hi = yi1 - yi0 + 1.0f;
  const float cxi = 0.5f*(xi0+xi1), cyi = 0.5f*(yi0+yi1);
  const float xj0 = bbox[j*4+0], yj0 = bbox[j*4+1], xj1 = bbox[j*4+2], yj1 = bbox[j*4+3];
  const float wj = xj1 - xj0 + 1.0f, hj = yj1 - yj0 + 1.0f;
  const float cxj = 0.5f*(xj0+xj1), cyj = 0.5f*(yj0+yj1);

  float pos[4];
  pos[0] = __logf(fmaxf(fabsf((cxi - cxj) / wi), 1e-3f));
  pos[1] = __logf(fmaxf(fabsf((cyi - cyj) / hi), 1e-3f));
  pos[2] = __logf(fmaxf(fabsf(wi / wj), 1e-3f));
  pos[3] = __logf(fmaxf(fabsf(hi / hj), 1e-3f));

  // 1000^(-r/8)
  const float invdim[8] = {1.0f, 0.42169650342858224f, 0.17782794100389228f,
      0.07498942093324558f, 0.03162277660168379f, 0.01333521432163324f,
      0.005623413251903491f, 0.0023713737056616554f};

  float acc[16];
#pragma unroll
  for (int g = 0; g < 16; ++g) acc[g] = bpS[g];

#pragma unroll
  for (int c = 0; c < 4; ++c) {
#pragma unroll
    for (int r = 0; r < 8; ++r) {
      float s, co;
      __sincosf(pos[c] * invdim[r], &s, &co);
      const float* w1 = &WpS[(c * 16 + r) * 16];       // sin weights
      const float* w2 = &WpS[(c * 16 + 8 + r) * 16];   // cos weights
#pragma unroll
      for (int g = 0; g < 16; ++g)
        acc[g] = fmaf(s, w1[g], fmaf(co, w2[g], acc[g]));
    }
  }
#pragma unroll
  for (int g = 0; g < 16; ++g)
    paff[((i * 16 + g) << 10) + j] = __logf(fmaxf(acc[g], 1e-6f));
}

// ---------------------------------------------------------------------------
// Kernel 4: per (g, 8-row i-tile): S = paff + QK^T/8, softmax_j, PV with RW.
// res[i][g*64+kk] = roi + b_conv + sm@RW.
// ---------------------------------------------------------------------------
__global__ __launch_bounds__(256) void attn_k(
    const float* __restrict__ q, const float* __restrict__ k,
    const float* __restrict__ RW, const float* __restrict__ paff,
    const float* __restrict__ roi, const float* __restrict__ bconv,
    float* __restrict__ res)
{
  const int g  = blockIdx.y;
  const int i0 = blockIdx.x * 8;
  const int t  = threadIdx.x;

  __shared__ float S[8][1024];      // 32 KB logits/probs
  __shared__ float Tile[64 * 68];   // union: KT[d][jj] pad65 / RT[jj][kk] pad68
  __shared__ float Qs[8][64];
  __shared__ float rinv[8];

  if (t < 128) {
    const int ii = t >> 4, d4 = (t & 15) * 4;
    *(float4*)&Qs[ii][d4] = *(const float4*)&q[(i0 + ii) * NN + g * DGD + d4];
  }

  const int jj  = t & 63;
  const int ii0 = (t >> 6) * 2, ii1 = ii0 + 1;
  const int sjj = t >> 2, sd4 = (t & 3) * 16;   // staging: 16 elems/thread

  // ---- phase 1: S = QK^T/8 + paff ----
  for (int jt = 0; jt < 16; ++jt) {
    const int j0 = jt * 64;
    const float* ksrc = k + (j0 + sjj) * NN + g * DGD + sd4;
    float4 v0 = *(const float4*)&ksrc[0];
    float4 v1 = *(const float4*)&ksrc[4];
    float4 v2 = *(const float4*)&ksrc[8];
    float4 v3 = *(const float4*)&ksrc[12];
    __syncthreads();
    {
      float tv[16] = {v0.x,v0.y,v0.z,v0.w, v1.x,v1.y,v1.z,v1.w,
                      v2.x,v2.y,v2.z,v2.w, v3.x,v3.y,v3.z,v3.w};
#pragma unroll
      for (int u = 0; u < 16; ++u) Tile[(sd4 + u) * 65 + sjj] = tv[u];  // transposed
    }
    __syncthreads();
    float a0 = 0.f, a1 = 0.f;
#pragma unroll
    for (int d = 0; d < 64; ++d) {
      const float kv = Tile[d * 65 + jj];
      a0 = fmaf(Qs[ii0][d], kv, a0);
      a1 = fmaf(Qs[ii1][d], kv, a1);
    }
    S[ii0][j0 + jj] = a0 * 0.125f + paff[((i0 + ii0) * GG + g) * NN + j0 + jj];
    S[ii1][j0 + jj] = a1 * 0.125f + paff[((i0 + ii1) * GG + g) * NN + j0 + jj];
  }
  __syncthreads();

  // ---- phase 2: softmax per row (wave w owns rows 2w, 2w+1) ----
  {
    const int w = t >> 6, l = t & 63;
#pragma unroll
    for (int rr = 0; rr < 2; ++rr) {
      const int r = w * 2 + rr;
      float m = -1e30f;
      for (int c = l; c < NN; c += 64) m = fmaxf(m, S[r][c]);
#pragma unroll
      for (int off = 32; off > 0; off >>= 1) m = fmaxf(m, __shfl_xor(m, off, 64));
      float sum = 0.f;
      for (int c = l; c < NN; c += 64) {
        const float e = __expf(S[r][c] - m);
        S[r][c] = e;
        sum += e;
      }
#pragma unroll
      for (int off = 32; off > 0; off >>= 1) sum += __shfl_xor(sum, off, 64);
      if (l == 0) rinv[r] = 1.0f / sum;
    }
  }

  // ---- phase 3: PV with RW tiles ----
  const int kk = t & 63;
  float o0 = 0.f, o1 = 0.f;
  for (int jt = 0; jt < 16; ++jt) {
    const int j0 = jt * 64;
    const float* rsrc = RW + (size_t)g * NN * DGD + (j0 + sjj) * DGD + sd4;
    float4 v0 = *(const float4*)&rsrc[0];
    float4 v1 = *(const float4*)&rsrc[4];
    float4 v2 = *(const float4*)&rsrc[8];
    float4 v3 = *(const float4*)&rsrc[12];
    __syncthreads();
    *(float4*)&Tile[sjj * 68 + sd4]      = v0;
    *(float4*)&Tile[sjj * 68 + sd4 + 4]  = v1;
    *(float4*)&Tile[sjj * 68 + sd4 + 8]  = v2;
    *(float4*)&Tile[sjj * 68 + sd4 + 12] = v3;
    __syncthreads();
#pragma unroll
    for (int j = 0; j < 64; ++j) {
      const float rv = Tile[j * 68 + kk];
      o0 = fmaf(S[ii0][j0 + j], rv, o0);
      o1 = fmaf(S[ii1][j0 + j], rv, o1);
    }
  }

  // ---- epilogue: residual + bias, scaled by 1/rowsum ----
  const int f = g * DGD + kk;
  res[(i0 + ii0) * NN + f] = roi[(i0 + ii0) * NN + f] + bconv[f] + o0 * rinv[ii0];
  res[(i0 + ii1) * NN + f] = roi[(i0 + ii1) * NN + f] + bconv[f] + o1 * rinv[ii1];
}

// ---------------------------------------------------------------------------
// Kernel 5a: partial column sums of res (8 row-chunks of 128)
// ---------------------------------------------------------------------------
__global__ __launch_bounds__(256) void colsum_partial_k(
    const float* __restrict__ res, float* __restrict__ part)
{
  const int d  = blockIdx.x * 256 + threadIdx.x;
  const int r0 = blockIdx.y * 128;
  float s0 = 0.f, s1 = 0.f, s2 = 0.f, s3 = 0.f;
  for (int i = 0; i < 128; i += 4) {
    s0 += res[(r0 + i    ) * NN + d];
    s1 += res[(r0 + i + 1) * NN + d];
    s2 += res[(r0 + i + 2) * NN + d];
    s3 += res[(r0 + i + 3) * NN + d];
  }
  part[blockIdx.y * NN + d] = (s0 + s1) + (s2 + s3);
}

// ---------------------------------------------------------------------------
// Kernel 5b: reduce partials, logits = colsum@W_ro + b_ro, sigmoid.
// ---------------------------------------------------------------------------
__global__ __launch_bounds__(1024) void final_k(
    const float* __restrict__ part, const float* __restrict__ W_ro,
    const float* __restrict__ b_ro, float* __restrict__ out)
{
  __shared__ float cs[1024];
  const int t = threadIdx.x;
  float s = 0.f;
#pragma unroll
  for (int p = 0; p < 8; ++p) s += part[p * NN + t];
  cs[t] = s;
  __syncthreads();
  if (t < CLS) {
    float lg = b_ro[t];
    for (int d = 0; d < 1024; ++d) lg = fmaf(cs[d], W_ro[d * CLS + t], lg);
    out[t] = 1.0f / (1.0f + __expf(-lg));
  }
}

// ---------------------------------------------------------------------------
extern "C" void kernel_launch(void* const* d_in, const int* in_sizes, int n_in,
                              void* d_out, int out_size, void* d_ws, size_t ws_size,
                              hipStream_t stream) {
  const float* bbox  = (const float*)d_in[0];
  const float* roi   = (const float*)d_in[1];
  const float* W_pos = (const float*)d_in[2];
  const float* b_pos = (const float*)d_in[3];
  const float* Wq    = (const float*)d_in[4];
  const float* bq    = (const float*)d_in[5];
  const float* Wk    = (const float*)d_in[6];
  const float* bk    = (const float*)d_in[7];
  const float* Wc    = (const float*)d_in[8];
  const float* bcv   = (const float*)d_in[9];
  const float* W_ro  = (const float*)d_in[10];
  const float* b_ro  = (const float*)d_in[11];

  float* ws   = (float*)d_ws;
  float* q    = ws;                 // 1M floats
  float* kbuf = ws + (1 << 20);     // 1M
  float* RW   = ws + (2 << 20);     // 1M
  float* res  = ws + (3 << 20);     // 1M
  float* part = ws + (4 << 20);     // 8K
  float* paff = ws + (5 << 20);     // 16M  (N*G*N)

  gemm_qk_k<<<dim3(16, 16, 2), 256, 0, stream>>>(roi, Wq, bq, Wk, bk, q, kbuf);
  gemm_rw_k<<<dim3(16, 16), 256, 0, stream>>>(roi, Wc, RW);
  posaff_k<<<dim3(4, 1024), 256, 0, stream>>>(bbox, W_pos, b_pos, paff);
  attn_k<<<dim3(128, 16), 256, 0, stream>>>(q, kbuf, RW, paff, roi, bcv, res);
  colsum_partial_k<<<dim3(4, 8), 256, 0, stream>>>(res, part);
  final_k<<<1, 1024, 0, stream>>>(part, W_ro, b_ro, (float*)d_out);
}

// Round 2
// 321.331 us; speedup vs baseline: 1.3832x; 1.3832x over previous
//
#include <hip/hip_runtime.h>
#include <hip/hip_bf16.h>
#include <math.h>

#define NN   1024
#define GG   16
#define DGD  64
#define CLS  80

// ---------------------------------------------------------------------------
// Kernel 1: q = roi@Wq + bq ; k = roi@Wk + bk   (blockIdx.z selects q/k)
// BM=BN=64, BK=32, 256 threads, 4x4 per thread.
// ---------------------------------------------------------------------------
__global__ __launch_bounds__(256) void gemm_qk_k(
    const float* __restrict__ A,
    const float* __restrict__ W0, const float* __restrict__ b0,
    const float* __restrict__ W1, const float* __restrict__ b1,
    float* __restrict__ C0, float* __restrict__ C1)
{
  const float* W    = blockIdx.z ? W1 : W0;
  const float* bias = blockIdx.z ? b1 : b0;
  float*       C    = blockIdx.z ? C1 : C0;
  const int j0 = blockIdx.x * 64;
  const int i0 = blockIdx.y * 64;
  const int t  = threadIdx.x;
  const int tx = t & 15, ty = t >> 4;

  __shared__ float As[64][36];   // pad 36: float4-aligned rows
  __shared__ float Bs[32][68];

  float acc[4][4] = {};

  const int ar = t >> 2, ac = (t & 3) * 8;   // A tile: 64x32
  const int br = t >> 3, bc = (t & 7) * 8;   // B tile: 32x64

  for (int kt = 0; kt < 32; ++kt) {
    const int k0 = kt * 32;
    float4 a0 = *(const float4*)&A[(i0 + ar) * NN + k0 + ac];
    float4 a1 = *(const float4*)&A[(i0 + ar) * NN + k0 + ac + 4];
    float4 w0 = *(const float4*)&W[(k0 + br) * NN + j0 + bc];
    float4 w1 = *(const float4*)&W[(k0 + br) * NN + j0 + bc + 4];
    __syncthreads();
    *(float4*)&As[ar][ac]     = a0;
    *(float4*)&As[ar][ac + 4] = a1;
    *(float4*)&Bs[br][bc]     = w0;
    *(float4*)&Bs[br][bc + 4] = w1;
    __syncthreads();
#pragma unroll
    for (int kk = 0; kk < 32; ++kk) {
      float av[4], bv[4];
#pragma unroll
      for (int im = 0; im < 4; ++im) av[im] = As[ty * 4 + im][kk];
#pragma unroll
      for (int in = 0; in < 4; ++in) bv[in] = Bs[kk][tx * 4 + in];
#pragma unroll
      for (int im = 0; im < 4; ++im)
#pragma unroll
        for (int in = 0; in < 4; ++in)
          acc[im][in] = fmaf(av[im], bv[in], acc[im][in]);
    }
  }
#pragma unroll
  for (int im = 0; im < 4; ++im) {
    const int row = i0 + ty * 4 + im;
    const int col = j0 + tx * 4;
    float4 o;
    o.x = acc[im][0] + bias[col + 0];
    o.y = acc[im][1] + bias[col + 1];
    o.z = acc[im][2] + bias[col + 2];
    o.w = acc[im][3] + bias[col + 3];
    *(float4*)&C[row * NN + col] = o;
  }
}

// ---------------------------------------------------------------------------
// Kernel 2: RW[g][j][kk] = sum_d roi[j][d] * W_conv[g][kk][d]   (NT GEMM)
// ---------------------------------------------------------------------------
__global__ __launch_bounds__(256) void gemm_rw_k(
    const float* __restrict__ roi, const float* __restrict__ Wc,
    float* __restrict__ RW)
{
  const int g  = blockIdx.y;
  const int j0 = blockIdx.x * 64;
  const int t  = threadIdx.x;
  const int tx = t & 15, ty = t >> 4;

  __shared__ float As[64][33];
  __shared__ float Bs[64][33];

  float acc[4][4] = {};
  const int r = t >> 2, c8 = (t & 3) * 8;
  const float* Wg = Wc + (size_t)g * DGD * NN;

  for (int dt = 0; dt < 32; ++dt) {
    const int d0 = dt * 32;
    float4 a0 = *(const float4*)&roi[(j0 + r) * NN + d0 + c8];
    float4 a1 = *(const float4*)&roi[(j0 + r) * NN + d0 + c8 + 4];
    float4 w0 = *(const float4*)&Wg[r * NN + d0 + c8];
    float4 w1 = *(const float4*)&Wg[r * NN + d0 + c8 + 4];
    __syncthreads();
    As[r][c8+0]=a0.x; As[r][c8+1]=a0.y; As[r][c8+2]=a0.z; As[r][c8+3]=a0.w;
    As[r][c8+4]=a1.x; As[r][c8+5]=a1.y; As[r][c8+6]=a1.z; As[r][c8+7]=a1.w;
    Bs[r][c8+0]=w0.x; Bs[r][c8+1]=w0.y; Bs[r][c8+2]=w0.z; Bs[r][c8+3]=w0.w;
    Bs[r][c8+4]=w1.x; Bs[r][c8+5]=w1.y; Bs[r][c8+6]=w1.z; Bs[r][c8+7]=w1.w;
    __syncthreads();
#pragma unroll
    for (int dd = 0; dd < 32; ++dd) {
      float av[4], bv[4];
#pragma unroll
      for (int im = 0; im < 4; ++im) av[im] = As[ty * 4 + im][dd];
#pragma unroll
      for (int in = 0; in < 4; ++in) bv[in] = Bs[tx * 4 + in][dd];
#pragma unroll
      for (int im = 0; im < 4; ++im)
#pragma unroll
        for (int in = 0; in < 4; ++in)
          acc[im][in] = fmaf(av[im], bv[in], acc[im][in]);
    }
  }
#pragma unroll
  for (int im = 0; im < 4; ++im) {
    float4 o; o.x = acc[im][0]; o.y = acc[im][1]; o.z = acc[im][2]; o.w = acc[im][3];
    *(float4*)&RW[(size_t)g * NN * DGD + (j0 + ty * 4 + im) * DGD + tx * 4] = o;
  }
}

// ---------------------------------------------------------------------------
// Kernel 3: paff[i][g][j] = log(max(relu(emb(i,j)@W_pos + b_pos), 1e-6))
// ---------------------------------------------------------------------------
__global__ __launch_bounds__(256) void posaff_k(
    const float* __restrict__ bbox, const float* __restrict__ Wp,
    const float* __restrict__ bp, float* __restrict__ paff)
{
  const int i = blockIdx.y;
  const int j = blockIdx.x * 256 + threadIdx.x;

  __shared__ float WpS[1024];
  __shared__ float bpS[16];
  for (int u = threadIdx.x; u < 1024; u += 256) WpS[u] = Wp[u];
  if (threadIdx.x < 16) bpS[threadIdx.x] = bp[threadIdx.x];
  __syncthreads();

  const float xi0 = bbox[i*4+0], yi0 = bbox[i*4+1], xi1 = bbox[i*4+2], yi1 = bbox[i*4+3];
  const float wi = xi1 - xi0 + 1.0f, hi = yi1 - yi0 + 1.0f;
  const float cxi = 0.5f*(xi0+xi1), cyi = 0.5f*(yi0+yi1);
  const float xj0 = bbox[j*4+0], yj0 = bbox[j*4+1], xj1 = bbox[j*4+2], yj1 = bbox[j*4+3];
  const float wj = xj1 - xj0 + 1.0f, hj = yj1 - yj0 + 1.0f;
  const float cxj = 0.5f*(xj0+xj1), cyj = 0.5f*(yj0+yj1);

  float pos[4];
  pos[0] = __logf(fmaxf(fabsf((cxi - cxj) / wi), 1e-3f));
  pos[1] = __logf(fmaxf(fabsf((cyi - cyj) / hi), 1e-3f));
  pos[2] = __logf(fmaxf(fabsf(wi / wj), 1e-3f));
  pos[3] = __logf(fmaxf(fabsf(hi / hj), 1e-3f));

  const float invdim[8] = {1.0f, 0.42169650342858224f, 0.17782794100389228f,
      0.07498942093324558f, 0.03162277660168379f, 0.01333521432163324f,
      0.005623413251903491f, 0.0023713737056616554f};

  float acc[16];
#pragma unroll
  for (int g = 0; g < 16; ++g) acc[g] = bpS[g];

#pragma unroll
  for (int c = 0; c < 4; ++c) {
#pragma unroll
    for (int r = 0; r < 8; ++r) {
      float s, co;
      __sincosf(pos[c] * invdim[r], &s, &co);
      const float* w1 = &WpS[(c * 16 + r) * 16];
      const float* w2 = &WpS[(c * 16 + 8 + r) * 16];
#pragma unroll
      for (int g = 0; g < 16; ++g)
        acc[g] = fmaf(s, w1[g], fmaf(co, w2[g], acc[g]));
    }
  }
#pragma unroll
  for (int g = 0; g < 16; ++g)
    paff[((i * 16 + g) << 10) + j] = __logf(fmaxf(acc[g], 1e-6f));
}

// ---------------------------------------------------------------------------
// Kernel 4 (REWRITTEN): flash-style. Block = 64 i-rows x 1 group.
// Register 4x4 microtiles for QK^T and PV; online softmax in registers
// (row stats via shfl within 16-lane row groups). LDS: QT + shared K/RW
// buffer + PT = 52 KB -> 3 blocks/CU.
// ---------------------------------------------------------------------------
__global__ __launch_bounds__(256) void attn_k(
    const float* __restrict__ q, const float* __restrict__ k,
    const float* __restrict__ RW, const float* __restrict__ paff,
    const float* __restrict__ roi, const float* __restrict__ bconv,
    float* __restrict__ res)
{
  const int g  = blockIdx.y;
  const int i0 = blockIdx.x * 64;
  const int t  = threadIdx.x;
  const int tx = t & 15, ty = t >> 4;

  __shared__ float QT[64][68];    // Q transposed: QT[d][row]
  __shared__ float KRW[64][68];   // K-tile transposed KT[d][j], then RW[j][kk]
  __shared__ float PT[64][68];    // P transposed: PT[j][row]

  // staging split: 256 threads x 16 floats = one 64x64 tile
  const int sr = t >> 2;            // 0..63 row within tile
  const int sc = (t & 3) * 16;      // col offset (16 elems)

  // ---- stage Q transposed (once) ----
  {
    const float* qsrc = q + (i0 + sr) * NN + g * DGD + sc;
    float4 v0 = *(const float4*)&qsrc[0];
    float4 v1 = *(const float4*)&qsrc[4];
    float4 v2 = *(const float4*)&qsrc[8];
    float4 v3 = *(const float4*)&qsrc[12];
    float tv[16] = {v0.x,v0.y,v0.z,v0.w, v1.x,v1.y,v1.z,v1.w,
                    v2.x,v2.y,v2.z,v2.w, v3.x,v3.y,v3.z,v3.w};
#pragma unroll
    for (int u = 0; u < 16; ++u) QT[sc + u][sr] = tv[u];
  }

  float m[4], l[4], o[4][4];
#pragma unroll
  for (int im = 0; im < 4; ++im) {
    m[im] = -1e30f; l[im] = 0.f;
#pragma unroll
    for (int in = 0; in < 4; ++in) o[im][in] = 0.f;
  }

  const float* rwg = RW + (size_t)g * NN * DGD;

#pragma unroll 1
  for (int jt = 0; jt < 16; ++jt) {
    const int j0 = jt * 64;
    // issue global loads early (K tile, RW tile, paff microtile)
    const float* ksrc = k + (j0 + sr) * NN + g * DGD + sc;
    float4 kv0 = *(const float4*)&ksrc[0];
    float4 kv1 = *(const float4*)&ksrc[4];
    float4 kv2 = *(const float4*)&ksrc[8];
    float4 kv3 = *(const float4*)&ksrc[12];
    const float* rsrc = rwg + (j0 + sr) * DGD + sc;
    float4 rv0 = *(const float4*)&rsrc[0];
    float4 rv1 = *(const float4*)&rsrc[4];
    float4 rv2 = *(const float4*)&rsrc[8];
    float4 rv3 = *(const float4*)&rsrc[12];
    float4 pf[4];
#pragma unroll
    for (int im = 0; im < 4; ++im)
      pf[im] = *(const float4*)&paff[(((i0 + ty * 4 + im) * GG + g) << 10) + j0 + tx * 4];

    __syncthreads();   // A: prev tile's PV readers done with KRW/PT
    {
      float tv[16] = {kv0.x,kv0.y,kv0.z,kv0.w, kv1.x,kv1.y,kv1.z,kv1.w,
                      kv2.x,kv2.y,kv2.z,kv2.w, kv3.x,kv3.y,kv3.z,kv3.w};
#pragma unroll
      for (int u = 0; u < 16; ++u) KRW[sc + u][sr] = tv[u];  // KT[d][j]
    }
    __syncthreads();   // B: KT visible

    // ---- QK^T: s[4][4] over K=64 ----
    float s[4][4] = {};
#pragma unroll 8
    for (int d = 0; d < 64; ++d) {
      float4 a = *(const float4*)&QT[d][ty * 4];
      float4 b = *(const float4*)&KRW[d][tx * 4];
      s[0][0] = fmaf(a.x, b.x, s[0][0]); s[0][1] = fmaf(a.x, b.y, s[0][1]);
      s[0][2] = fmaf(a.x, b.z, s[0][2]); s[0][3] = fmaf(a.x, b.w, s[0][3]);
      s[1][0] = fmaf(a.y, b.x, s[1][0]); s[1][1] = fmaf(a.y, b.y, s[1][1]);
      s[1][2] = fmaf(a.y, b.z, s[1][2]); s[1][3] = fmaf(a.y, b.w, s[1][3]);
      s[2][0] = fmaf(a.z, b.x, s[2][0]); s[2][1] = fmaf(a.z, b.y, s[2][1]);
      s[2][2] = fmaf(a.z, b.z, s[2][2]); s[2][3] = fmaf(a.z, b.w, s[2][3]);
      s[3][0] = fmaf(a.w, b.x, s[3][0]); s[3][1] = fmaf(a.w, b.y, s[3][1]);
      s[3][2] = fmaf(a.w, b.z, s[3][2]); s[3][3] = fmaf(a.w, b.w, s[3][3]);
    }

    // ---- online softmax update (registers + shfl in 16-lane row group) ----
#pragma unroll
    for (int im = 0; im < 4; ++im) {
      float* pp = (float*)&pf[im];
      s[im][0] = fmaf(s[im][0], 0.125f, pp[0]);
      s[im][1] = fmaf(s[im][1], 0.125f, pp[1]);
      s[im][2] = fmaf(s[im][2], 0.125f, pp[2]);
      s[im][3] = fmaf(s[im][3], 0.125f, pp[3]);
      float tmax = fmaxf(fmaxf(s[im][0], s[im][1]), fmaxf(s[im][2], s[im][3]));
#pragma unroll
      for (int off = 1; off < 16; off <<= 1) tmax = fmaxf(tmax, __shfl_xor(tmax, off, 64));
      const float mnew = fmaxf(m[im], tmax);
      const float sc_  = __expf(m[im] - mnew);
      s[im][0] = __expf(s[im][0] - mnew);
      s[im][1] = __expf(s[im][1] - mnew);
      s[im][2] = __expf(s[im][2] - mnew);
      s[im][3] = __expf(s[im][3] - mnew);
      float tsum = (s[im][0] + s[im][1]) + (s[im][2] + s[im][3]);
#pragma unroll
      for (int off = 1; off < 16; off <<= 1) tsum += __shfl_xor(tsum, off, 64);
      l[im] = l[im] * sc_ + tsum;
      o[im][0] *= sc_; o[im][1] *= sc_; o[im][2] *= sc_; o[im][3] *= sc_;
      m[im] = mnew;
    }

    __syncthreads();   // C: QK readers done with KRW
    // write RW tile (direct layout) and P transposed
    *(float4*)&KRW[sr][sc + 0]  = rv0;
    *(float4*)&KRW[sr][sc + 4]  = rv1;
    *(float4*)&KRW[sr][sc + 8]  = rv2;
    *(float4*)&KRW[sr][sc + 12] = rv3;
#pragma unroll
    for (int jj = 0; jj < 4; ++jj) {
      float4 pv4; pv4.x = s[0][jj]; pv4.y = s[1][jj]; pv4.z = s[2][jj]; pv4.w = s[3][jj];
      *(float4*)&PT[tx * 4 + jj][ty * 4] = pv4;
    }
    __syncthreads();   // D: RW + PT visible

    // ---- PV: o += P^T-tile x RW-tile ----
#pragma unroll 8
    for (int j = 0; j < 64; ++j) {
      float4 a = *(const float4*)&PT[j][ty * 4];
      float4 b = *(const float4*)&KRW[j][tx * 4];
      o[0][0] = fmaf(a.x, b.x, o[0][0]); o[0][1] = fmaf(a.x, b.y, o[0][1]);
      o[0][2] = fmaf(a.x, b.z, o[0][2]); o[0][3] = fmaf(a.x, b.w, o[0][3]);
      o[1][0] = fmaf(a.y, b.x, o[1][0]); o[1][1] = fmaf(a.y, b.y, o[1][1]);
      o[1][2] = fmaf(a.y, b.z, o[1][2]); o[1][3] = fmaf(a.y, b.w, o[1][3]);
      o[2][0] = fmaf(a.z, b.x, o[2][0]); o[2][1] = fmaf(a.z, b.y, o[2][1]);
      o[2][2] = fmaf(a.z, b.z, o[2][2]); o[2][3] = fmaf(a.z, b.w, o[2][3]);
      o[3][0] = fmaf(a.w, b.x, o[3][0]); o[3][1] = fmaf(a.w, b.y, o[3][1]);
      o[3][2] = fmaf(a.w, b.z, o[3][2]); o[3][3] = fmaf(a.w, b.w, o[3][3]);
    }
  }

  // ---- epilogue ----
#pragma unroll
  for (int im = 0; im < 4; ++im) {
    const float rinv = 1.0f / l[im];
    const int row = i0 + ty * 4 + im;
    const int f   = g * DGD + tx * 4;
    float4 r4 = *(const float4*)&roi[row * NN + f];
    float4 b4 = *(const float4*)&bconv[f];
    float4 ov;
    ov.x = r4.x + b4.x + o[im][0] * rinv;
    ov.y = r4.y + b4.y + o[im][1] * rinv;
    ov.z = r4.z + b4.z + o[im][2] * rinv;
    ov.w = r4.w + b4.w + o[im][3] * rinv;
    *(float4*)&res[row * NN + f] = ov;
  }
}

// ---------------------------------------------------------------------------
// Kernel 5a: partial column sums of res
// ---------------------------------------------------------------------------
__global__ __launch_bounds__(256) void colsum_partial_k(
    const float* __restrict__ res, float* __restrict__ part)
{
  const int d  = blockIdx.x * 256 + threadIdx.x;
  const int r0 = blockIdx.y * 128;
  float s0 = 0.f, s1 = 0.f, s2 = 0.f, s3 = 0.f;
  for (int i = 0; i < 128; i += 4) {
    s0 += res[(r0 + i    ) * NN + d];
    s1 += res[(r0 + i + 1) * NN + d];
    s2 += res[(r0 + i + 2) * NN + d];
    s3 += res[(r0 + i + 3) * NN + d];
  }
  part[blockIdx.y * NN + d] = (s0 + s1) + (s2 + s3);
}

// ---------------------------------------------------------------------------
// Kernel 5b: reduce partials, logits = colsum@W_ro + b_ro, sigmoid.
// ---------------------------------------------------------------------------
__global__ __launch_bounds__(1024) void final_k(
    const float* __restrict__ part, const float* __restrict__ W_ro,
    const float* __restrict__ b_ro, float* __restrict__ out)
{
  __shared__ float cs[1024];
  const int t = threadIdx.x;
  float s = 0.f;
#pragma unroll
  for (int p = 0; p < 8; ++p) s += part[p * NN + t];
  cs[t] = s;
  __syncthreads();
  if (t < CLS) {
    float lg = b_ro[t];
    for (int d = 0; d < 1024; ++d) lg = fmaf(cs[d], W_ro[d * CLS + t], lg);
    out[t] = 1.0f / (1.0f + __expf(-lg));
  }
}

// ---------------------------------------------------------------------------
extern "C" void kernel_launch(void* const* d_in, const int* in_sizes, int n_in,
                              void* d_out, int out_size, void* d_ws, size_t ws_size,
                              hipStream_t stream) {
  const float* bbox  = (const float*)d_in[0];
  const float* roi   = (const float*)d_in[1];
  const float* W_pos = (const float*)d_in[2];
  const float* b_pos = (const float*)d_in[3];
  const float* Wq    = (const float*)d_in[4];
  const float* bq    = (const float*)d_in[5];
  const float* Wk    = (const float*)d_in[6];
  const float* bk    = (const float*)d_in[7];
  const float* Wc    = (const float*)d_in[8];
  const float* bcv   = (const float*)d_in[9];
  const float* W_ro  = (const float*)d_in[10];
  const float* b_ro  = (const float*)d_in[11];

  float* ws   = (float*)d_ws;
  float* q    = ws;                 // 1M floats
  float* kbuf = ws + (1 << 20);     // 1M
  float* RW   = ws + (2 << 20);     // 1M
  float* res  = ws + (3 << 20);     // 1M
  float* part = ws + (4 << 20);     // 8K
  float* paff = ws + (5 << 20);     // 16M  (N*G*N)

  gemm_qk_k<<<dim3(16, 16, 2), 256, 0, stream>>>(roi, Wq, bq, Wk, bk, q, kbuf);
  gemm_rw_k<<<dim3(16, 16), 256, 0, stream>>>(roi, Wc, RW);
  posaff_k<<<dim3(4, 1024), 256, 0, stream>>>(bbox, W_pos, b_pos, paff);
  attn_k<<<dim3(16, 16), 256, 0, stream>>>(q, kbuf, RW, paff, roi, bcv, res);
  colsum_partial_k<<<dim3(4, 8), 256, 0, stream>>>(res, part);
  final_k<<<1, 1024, 0, stream>>>(part, W_ro, b_ro, (float*)d_out);
}

// Round 3
// 297.109 us; speedup vs baseline: 1.4959x; 1.0815x over previous
//
#include <hip/hip_runtime.h>
#include <hip/hip_bf16.h>
#include <math.h>

#define NN   1024
#define GG   16
#define DGD  64
#define CLS  80
#define SPLIT 4
#define JT_PER 4   // 16 j-tiles / SPLIT

// ---------------------------------------------------------------------------
// Kernel 1: q = roi@Wq + bq ; k = roi@Wk + bk   (blockIdx.z selects q/k)
// ---------------------------------------------------------------------------
__global__ __launch_bounds__(256) void gemm_qk_k(
    const float* __restrict__ A,
    const float* __restrict__ W0, const float* __restrict__ b0,
    const float* __restrict__ W1, const float* __restrict__ b1,
    float* __restrict__ C0, float* __restrict__ C1)
{
  const float* W    = blockIdx.z ? W1 : W0;
  const float* bias = blockIdx.z ? b1 : b0;
  float*       C    = blockIdx.z ? C1 : C0;
  const int j0 = blockIdx.x * 64;
  const int i0 = blockIdx.y * 64;
  const int t  = threadIdx.x;
  const int tx = t & 15, ty = t >> 4;

  __shared__ float As[64][36];
  __shared__ float Bs[32][68];

  float acc[4][4] = {};

  const int ar = t >> 2, ac = (t & 3) * 8;
  const int br = t >> 3, bc = (t & 7) * 8;

  for (int kt = 0; kt < 32; ++kt) {
    const int k0 = kt * 32;
    float4 a0 = *(const float4*)&A[(i0 + ar) * NN + k0 + ac];
    float4 a1 = *(const float4*)&A[(i0 + ar) * NN + k0 + ac + 4];
    float4 w0 = *(const float4*)&W[(k0 + br) * NN + j0 + bc];
    float4 w1 = *(const float4*)&W[(k0 + br) * NN + j0 + bc + 4];
    __syncthreads();
    *(float4*)&As[ar][ac]     = a0;
    *(float4*)&As[ar][ac + 4] = a1;
    *(float4*)&Bs[br][bc]     = w0;
    *(float4*)&Bs[br][bc + 4] = w1;
    __syncthreads();
#pragma unroll
    for (int kk = 0; kk < 32; ++kk) {
      float av[4], bv[4];
#pragma unroll
      for (int im = 0; im < 4; ++im) av[im] = As[ty * 4 + im][kk];
#pragma unroll
      for (int in = 0; in < 4; ++in) bv[in] = Bs[kk][tx * 4 + in];
#pragma unroll
      for (int im = 0; im < 4; ++im)
#pragma unroll
        for (int in = 0; in < 4; ++in)
          acc[im][in] = fmaf(av[im], bv[in], acc[im][in]);
    }
  }
#pragma unroll
  for (int im = 0; im < 4; ++im) {
    const int row = i0 + ty * 4 + im;
    const int col = j0 + tx * 4;
    float4 o;
    o.x = acc[im][0] + bias[col + 0];
    o.y = acc[im][1] + bias[col + 1];
    o.z = acc[im][2] + bias[col + 2];
    o.w = acc[im][3] + bias[col + 3];
    *(float4*)&C[row * NN + col] = o;
  }
}

// ---------------------------------------------------------------------------
// Kernel 2: RW[g][j][kk] = sum_d roi[j][d] * W_conv[g][kk][d]   (NT GEMM)
// ---------------------------------------------------------------------------
__global__ __launch_bounds__(256) void gemm_rw_k(
    const float* __restrict__ roi, const float* __restrict__ Wc,
    float* __restrict__ RW)
{
  const int g  = blockIdx.y;
  const int j0 = blockIdx.x * 64;
  const int t  = threadIdx.x;
  const int tx = t & 15, ty = t >> 4;

  __shared__ float As[64][33];
  __shared__ float Bs[64][33];

  float acc[4][4] = {};
  const int r = t >> 2, c8 = (t & 3) * 8;
  const float* Wg = Wc + (size_t)g * DGD * NN;

  for (int dt = 0; dt < 32; ++dt) {
    const int d0 = dt * 32;
    float4 a0 = *(const float4*)&roi[(j0 + r) * NN + d0 + c8];
    float4 a1 = *(const float4*)&roi[(j0 + r) * NN + d0 + c8 + 4];
    float4 w0 = *(const float4*)&Wg[r * NN + d0 + c8];
    float4 w1 = *(const float4*)&Wg[r * NN + d0 + c8 + 4];
    __syncthreads();
    As[r][c8+0]=a0.x; As[r][c8+1]=a0.y; As[r][c8+2]=a0.z; As[r][c8+3]=a0.w;
    As[r][c8+4]=a1.x; As[r][c8+5]=a1.y; As[r][c8+6]=a1.z; As[r][c8+7]=a1.w;
    Bs[r][c8+0]=w0.x; Bs[r][c8+1]=w0.y; Bs[r][c8+2]=w0.z; Bs[r][c8+3]=w0.w;
    Bs[r][c8+4]=w1.x; Bs[r][c8+5]=w1.y; Bs[r][c8+6]=w1.z; Bs[r][c8+7]=w1.w;
    __syncthreads();
#pragma unroll
    for (int dd = 0; dd < 32; ++dd) {
      float av[4], bv[4];
#pragma unroll
      for (int im = 0; im < 4; ++im) av[im] = As[ty * 4 + im][dd];
#pragma unroll
      for (int in = 0; in < 4; ++in) bv[in] = Bs[tx * 4 + in][dd];
#pragma unroll
      for (int im = 0; im < 4; ++im)
#pragma unroll
        for (int in = 0; in < 4; ++in)
          acc[im][in] = fmaf(av[im], bv[in], acc[im][in]);
    }
  }
#pragma unroll
  for (int im = 0; im < 4; ++im) {
    float4 o; o.x = acc[im][0]; o.y = acc[im][1]; o.z = acc[im][2]; o.w = acc[im][3];
    *(float4*)&RW[(size_t)g * NN * DGD + (j0 + ty * 4 + im) * DGD + tx * 4] = o;
  }
}

// ---------------------------------------------------------------------------
// Kernel 3: paff[i][g][j] = log(max(relu(emb(i,j)@W_pos + b_pos), 1e-6))
// ---------------------------------------------------------------------------
__global__ __launch_bounds__(256) void posaff_k(
    const float* __restrict__ bbox, const float* __restrict__ Wp,
    const float* __restrict__ bp, float* __restrict__ paff)
{
  const int i = blockIdx.y;
  const int j = blockIdx.x * 256 + threadIdx.x;

  __shared__ float WpS[1024];
  __shared__ float bpS[16];
  for (int u = threadIdx.x; u < 1024; u += 256) WpS[u] = Wp[u];
  if (threadIdx.x < 16) bpS[threadIdx.x] = bp[threadIdx.x];
  __syncthreads();

  const float xi0 = bbox[i*4+0], yi0 = bbox[i*4+1], xi1 = bbox[i*4+2], yi1 = bbox[i*4+3];
  const float wi = xi1 - xi0 + 1.0f, hi = yi1 - yi0 + 1.0f;
  const float cxi = 0.5f*(xi0+xi1), cyi = 0.5f*(yi0+yi1);
  const float xj0 = bbox[j*4+0], yj0 = bbox[j*4+1], xj1 = bbox[j*4+2], yj1 = bbox[j*4+3];
  const float wj = xj1 - xj0 + 1.0f, hj = yj1 - yj0 + 1.0f;
  const float cxj = 0.5f*(xj0+xj1), cyj = 0.5f*(yj0+yj1);

  float pos[4];
  pos[0] = __logf(fmaxf(fabsf((cxi - cxj) / wi), 1e-3f));
  pos[1] = __logf(fmaxf(fabsf((cyi - cyj) / hi), 1e-3f));
  pos[2] = __logf(fmaxf(fabsf(wi / wj), 1e-3f));
  pos[3] = __logf(fmaxf(fabsf(hi / hj), 1e-3f));

  const float invdim[8] = {1.0f, 0.42169650342858224f, 0.17782794100389228f,
      0.07498942093324558f, 0.03162277660168379f, 0.01333521432163324f,
      0.005623413251903491f, 0.0023713737056616554f};

  float acc[16];
#pragma unroll
  for (int g = 0; g < 16; ++g) acc[g] = bpS[g];

#pragma unroll
  for (int c = 0; c < 4; ++c) {
#pragma unroll
    for (int r = 0; r < 8; ++r) {
      float s, co;
      __sincosf(pos[c] * invdim[r], &s, &co);
      const float* w1 = &WpS[(c * 16 + r) * 16];
      const float* w2 = &WpS[(c * 16 + 8 + r) * 16];
#pragma unroll
      for (int g = 0; g < 16; ++g)
        acc[g] = fmaf(s, w1[g], fmaf(co, w2[g], acc[g]));
    }
  }
#pragma unroll
  for (int g = 0; g < 16; ++g)
    paff[((i * 16 + g) << 10) + j] = __logf(fmaxf(acc[g], 1e-6f));
}

// ---------------------------------------------------------------------------
// Kernel 4: flash attention, split-j. Block = (i-tile, g, split).
// Each block does JT_PER j-tiles, writes unnormalized partial o + (m,l).
// ---------------------------------------------------------------------------
__global__ __launch_bounds__(256) void attn_k(
    const float* __restrict__ q, const float* __restrict__ k,
    const float* __restrict__ RW, const float* __restrict__ paff,
    float* __restrict__ po, float* __restrict__ pstat)
{
  const int g  = blockIdx.y;
  const int i0 = blockIdx.x * 64;
  const int sp = blockIdx.z;
  const int t  = threadIdx.x;
  const int tx = t & 15, ty = t >> 4;

  __shared__ float QT[64][68];
  __shared__ float KRW[64][68];
  __shared__ float PT[64][68];

  const int sr = t >> 2;
  const int sc = (t & 3) * 16;

  // ---- stage Q transposed (once) ----
  {
    const float* qsrc = q + (i0 + sr) * NN + g * DGD + sc;
    float4 v0 = *(const float4*)&qsrc[0];
    float4 v1 = *(const float4*)&qsrc[4];
    float4 v2 = *(const float4*)&qsrc[8];
    float4 v3 = *(const float4*)&qsrc[12];
    float tv[16] = {v0.x,v0.y,v0.z,v0.w, v1.x,v1.y,v1.z,v1.w,
                    v2.x,v2.y,v2.z,v2.w, v3.x,v3.y,v3.z,v3.w};
#pragma unroll
    for (int u = 0; u < 16; ++u) QT[sc + u][sr] = tv[u];
  }

  float m[4], l[4], o[4][4];
#pragma unroll
  for (int im = 0; im < 4; ++im) {
    m[im] = -1e30f; l[im] = 0.f;
#pragma unroll
    for (int in = 0; in < 4; ++in) o[im][in] = 0.f;
  }

  const float* rwg = RW + (size_t)g * NN * DGD;

#pragma unroll 1
  for (int jt = sp * JT_PER; jt < sp * JT_PER + JT_PER; ++jt) {
    const int j0 = jt * 64;
    const float* ksrc = k + (j0 + sr) * NN + g * DGD + sc;
    float4 kv0 = *(const float4*)&ksrc[0];
    float4 kv1 = *(const float4*)&ksrc[4];
    float4 kv2 = *(const float4*)&ksrc[8];
    float4 kv3 = *(const float4*)&ksrc[12];
    const float* rsrc = rwg + (j0 + sr) * DGD + sc;
    float4 rv0 = *(const float4*)&rsrc[0];
    float4 rv1 = *(const float4*)&rsrc[4];
    float4 rv2 = *(const float4*)&rsrc[8];
    float4 rv3 = *(const float4*)&rsrc[12];
    float4 pf[4];
#pragma unroll
    for (int im = 0; im < 4; ++im)
      pf[im] = *(const float4*)&paff[(((i0 + ty * 4 + im) * GG + g) << 10) + j0 + tx * 4];

    __syncthreads();   // A: prev PV done with KRW/PT
    {
      float tv[16] = {kv0.x,kv0.y,kv0.z,kv0.w, kv1.x,kv1.y,kv1.z,kv1.w,
                      kv2.x,kv2.y,kv2.z,kv2.w, kv3.x,kv3.y,kv3.z,kv3.w};
#pragma unroll
      for (int u = 0; u < 16; ++u) KRW[sc + u][sr] = tv[u];
    }
    __syncthreads();   // B: KT visible

    float s[4][4] = {};
#pragma unroll 8
    for (int d = 0; d < 64; ++d) {
      float4 a = *(const float4*)&QT[d][ty * 4];
      float4 b = *(const float4*)&KRW[d][tx * 4];
      s[0][0] = fmaf(a.x, b.x, s[0][0]); s[0][1] = fmaf(a.x, b.y, s[0][1]);
      s[0][2] = fmaf(a.x, b.z, s[0][2]); s[0][3] = fmaf(a.x, b.w, s[0][3]);
      s[1][0] = fmaf(a.y, b.x, s[1][0]); s[1][1] = fmaf(a.y, b.y, s[1][1]);
      s[1][2] = fmaf(a.y, b.z, s[1][2]); s[1][3] = fmaf(a.y, b.w, s[1][3]);
      s[2][0] = fmaf(a.z, b.x, s[2][0]); s[2][1] = fmaf(a.z, b.y, s[2][1]);
      s[2][2] = fmaf(a.z, b.z, s[2][2]); s[2][3] = fmaf(a.z, b.w, s[2][3]);
      s[3][0] = fmaf(a.w, b.x, s[3][0]); s[3][1] = fmaf(a.w, b.y, s[3][1]);
      s[3][2] = fmaf(a.w, b.z, s[3][2]); s[3][3] = fmaf(a.w, b.w, s[3][3]);
    }

#pragma unroll
    for (int im = 0; im < 4; ++im) {
      float* pp = (float*)&pf[im];
      s[im][0] = fmaf(s[im][0], 0.125f, pp[0]);
      s[im][1] = fmaf(s[im][1], 0.125f, pp[1]);
      s[im][2] = fmaf(s[im][2], 0.125f, pp[2]);
      s[im][3] = fmaf(s[im][3], 0.125f, pp[3]);
      float tmax = fmaxf(fmaxf(s[im][0], s[im][1]), fmaxf(s[im][2], s[im][3]));
#pragma unroll
      for (int off = 1; off < 16; off <<= 1) tmax = fmaxf(tmax, __shfl_xor(tmax, off, 64));
      const float mnew = fmaxf(m[im], tmax);
      const float sc_  = __expf(m[im] - mnew);
      s[im][0] = __expf(s[im][0] - mnew);
      s[im][1] = __expf(s[im][1] - mnew);
      s[im][2] = __expf(s[im][2] - mnew);
      s[im][3] = __expf(s[im][3] - mnew);
      float tsum = (s[im][0] + s[im][1]) + (s[im][2] + s[im][3]);
#pragma unroll
      for (int off = 1; off < 16; off <<= 1) tsum += __shfl_xor(tsum, off, 64);
      l[im] = l[im] * sc_ + tsum;
      o[im][0] *= sc_; o[im][1] *= sc_; o[im][2] *= sc_; o[im][3] *= sc_;
      m[im] = mnew;
    }

    __syncthreads();   // C: QK readers done with KRW
    *(float4*)&KRW[sr][sc + 0]  = rv0;
    *(float4*)&KRW[sr][sc + 4]  = rv1;
    *(float4*)&KRW[sr][sc + 8]  = rv2;
    *(float4*)&KRW[sr][sc + 12] = rv3;
#pragma unroll
    for (int jj = 0; jj < 4; ++jj) {
      float4 pv4; pv4.x = s[0][jj]; pv4.y = s[1][jj]; pv4.z = s[2][jj]; pv4.w = s[3][jj];
      *(float4*)&PT[tx * 4 + jj][ty * 4] = pv4;
    }
    __syncthreads();   // D: RW + PT visible

#pragma unroll 8
    for (int j = 0; j < 64; ++j) {
      float4 a = *(const float4*)&PT[j][ty * 4];
      float4 b = *(const float4*)&KRW[j][tx * 4];
      o[0][0] = fmaf(a.x, b.x, o[0][0]); o[0][1] = fmaf(a.x, b.y, o[0][1]);
      o[0][2] = fmaf(a.x, b.z, o[0][2]); o[0][3] = fmaf(a.x, b.w, o[0][3]);
      o[1][0] = fmaf(a.y, b.x, o[1][0]); o[1][1] = fmaf(a.y, b.y, o[1][1]);
      o[1][2] = fmaf(a.y, b.z, o[1][2]); o[1][3] = fmaf(a.y, b.w, o[1][3]);
      o[2][0] = fmaf(a.z, b.x, o[2][0]); o[2][1] = fmaf(a.z, b.y, o[2][1]);
      o[2][2] = fmaf(a.z, b.z, o[2][2]); o[2][3] = fmaf(a.z, b.w, o[2][3]);
      o[3][0] = fmaf(a.w, b.x, o[3][0]); o[3][1] = fmaf(a.w, b.y, o[3][1]);
      o[3][2] = fmaf(a.w, b.z, o[3][2]); o[3][3] = fmaf(a.w, b.w, o[3][3]);
    }
  }

  // ---- epilogue: write unnormalized partials + stats ----
  const size_t idx = ((size_t)blockIdx.x * GG + g) * SPLIT + sp;
  float* pot = po + idx * 4096;
#pragma unroll
  for (int im = 0; im < 4; ++im) {
    float4 ov; ov.x = o[im][0]; ov.y = o[im][1]; ov.z = o[im][2]; ov.w = o[im][3];
    *(float4*)&pot[(ty * 4 + im) * 64 + tx * 4] = ov;
  }
  if (tx == 0) {
#pragma unroll
    for (int im = 0; im < 4; ++im) {
      float2 st; st.x = m[im]; st.y = l[im];
      *(float2*)&pstat[(idx * 64 + (ty * 4 + im)) * 2] = st;
    }
  }
}

// ---------------------------------------------------------------------------
// Kernel 4b: combine split partials -> res (+ residual + bias)
// ---------------------------------------------------------------------------
__global__ __launch_bounds__(256) void combine_k(
    const float* __restrict__ po, const float* __restrict__ pstat,
    const float* __restrict__ roi, const float* __restrict__ bconv,
    float* __restrict__ res)
{
  const int it = blockIdx.x, g = blockIdx.y;
  const int t = threadIdx.x;
  const int row = t >> 2, c0 = (t & 3) * 16;
  const size_t base = ((size_t)it * GG + g) * SPLIT;

  float ms[SPLIT], ls[SPLIT];
#pragma unroll
  for (int s = 0; s < SPLIT; ++s) {
    float2 st = *(const float2*)&pstat[((base + s) * 64 + row) * 2];
    ms[s] = st.x; ls[s] = st.y;
  }
  float M = fmaxf(fmaxf(ms[0], ms[1]), fmaxf(ms[2], ms[3]));
  float w[SPLIT], L = 0.f;
#pragma unroll
  for (int s = 0; s < SPLIT; ++s) { w[s] = __expf(ms[s] - M); L = fmaf(ls[s], w[s], L); }
  const float rL = 1.0f / L;

  const int grow = it * 64 + row;
  const int f0   = g * DGD + c0;
#pragma unroll
  for (int c = 0; c < 4; ++c) {
    float4 acc = {0.f, 0.f, 0.f, 0.f};
#pragma unroll
    for (int s = 0; s < SPLIT; ++s) {
      float4 v = *(const float4*)&po[(base + s) * 4096 + row * 64 + c0 + c * 4];
      acc.x = fmaf(v.x, w[s], acc.x);
      acc.y = fmaf(v.y, w[s], acc.y);
      acc.z = fmaf(v.z, w[s], acc.z);
      acc.w = fmaf(v.w, w[s], acc.w);
    }
    float4 r4 = *(const float4*)&roi[grow * NN + f0 + c * 4];
    float4 b4 = *(const float4*)&bconv[f0 + c * 4];
    float4 ov;
    ov.x = r4.x + b4.x + acc.x * rL;
    ov.y = r4.y + b4.y + acc.y * rL;
    ov.z = r4.z + b4.z + acc.z * rL;
    ov.w = r4.w + b4.w + acc.w * rL;
    *(float4*)&res[grow * NN + f0 + c * 4] = ov;
  }
}

// ---------------------------------------------------------------------------
// Kernel 5a: partial column sums of res
// ---------------------------------------------------------------------------
__global__ __launch_bounds__(256) void colsum_partial_k(
    const float* __restrict__ res, float* __restrict__ part)
{
  const int d  = blockIdx.x * 256 + threadIdx.x;
  const int r0 = blockIdx.y * 128;
  float s0 = 0.f, s1 = 0.f, s2 = 0.f, s3 = 0.f;
  for (int i = 0; i < 128; i += 4) {
    s0 += res[(r0 + i    ) * NN + d];
    s1 += res[(r0 + i + 1) * NN + d];
    s2 += res[(r0 + i + 2) * NN + d];
    s3 += res[(r0 + i + 3) * NN + d];
  }
  part[blockIdx.y * NN + d] = (s0 + s1) + (s2 + s3);
}

// ---------------------------------------------------------------------------
// Kernel 5b: reduce partials, logits = colsum@W_ro + b_ro, sigmoid.
// ---------------------------------------------------------------------------
__global__ __launch_bounds__(1024) void final_k(
    const float* __restrict__ part, const float* __restrict__ W_ro,
    const float* __restrict__ b_ro, float* __restrict__ out)
{
  __shared__ float cs[1024];
  const int t = threadIdx.x;
  float s = 0.f;
#pragma unroll
  for (int p = 0; p < 8; ++p) s += part[p * NN + t];
  cs[t] = s;
  __syncthreads();
  if (t < CLS) {
    float lg = b_ro[t];
    for (int d = 0; d < 1024; ++d) lg = fmaf(cs[d], W_ro[d * CLS + t], lg);
    out[t] = 1.0f / (1.0f + __expf(-lg));
  }
}

// ---------------------------------------------------------------------------
extern "C" void kernel_launch(void* const* d_in, const int* in_sizes, int n_in,
                              void* d_out, int out_size, void* d_ws, size_t ws_size,
                              hipStream_t stream) {
  const float* bbox  = (const float*)d_in[0];
  const float* roi   = (const float*)d_in[1];
  const float* W_pos = (const float*)d_in[2];
  const float* b_pos = (const float*)d_in[3];
  const float* Wq    = (const float*)d_in[4];
  const float* bq    = (const float*)d_in[5];
  const float* Wk    = (const float*)d_in[6];
  const float* bk    = (const float*)d_in[7];
  const float* Wc    = (const float*)d_in[8];
  const float* bcv   = (const float*)d_in[9];
  const float* W_ro  = (const float*)d_in[10];
  const float* b_ro  = (const float*)d_in[11];

  float* ws    = (float*)d_ws;
  float* q     = ws;                  // 1M floats
  float* kbuf  = ws + (1 << 20);      // 1M
  float* RW    = ws + (2 << 20);      // 1M
  float* res   = ws + (3 << 20);      // 1M
  float* part  = ws + (4 << 20);      // 8K
  float* paff  = ws + (5 << 20);      // 16M
  float* po    = ws + (21 << 20);     // 4M  (16*16*4 tiles * 4096)
  float* pstat = ws + (25 << 20);     // 128K

  gemm_qk_k<<<dim3(16, 16, 2), 256, 0, stream>>>(roi, Wq, bq, Wk, bk, q, kbuf);
  gemm_rw_k<<<dim3(16, 16), 256, 0, stream>>>(roi, Wc, RW);
  posaff_k<<<dim3(4, 1024), 256, 0, stream>>>(bbox, W_pos, b_pos, paff);
  attn_k<<<dim3(16, 16, SPLIT), 256, 0, stream>>>(q, kbuf, RW, paff, po, pstat);
  combine_k<<<dim3(16, 16), 256, 0, stream>>>(po, pstat, roi, bcv, res);
  colsum_partial_k<<<dim3(4, 8), 256, 0, stream>>>(res, part);
  final_k<<<1, 1024, 0, stream>>>(part, W_ro, b_ro, (float*)d_out);
}

// Round 4
// 266.394 us; speedup vs baseline: 1.6684x; 1.1153x over previous
//
#include <hip/hip_runtime.h>
#include <hip/hip_bf16.h>
#include <math.h>

#define NN   1024
#define GG   16
#define DGD  64
#define CLS  80
#define SPLIT 4
#define JT_PER 4   // 16 j-tiles / SPLIT

typedef __attribute__((ext_vector_type(8))) short short8;
typedef __attribute__((ext_vector_type(4))) float f32x4;

// bf16 split: x ~= hi + lo, each RNE-rounded bf16.
__device__ inline void split2(float x, ushort& h, ushort& l) {
  uint u = __float_as_uint(x);
  uint rh = (u + 0x7FFFu + ((u >> 16) & 1u)) >> 16;
  h = (ushort)rh;
  float r = x - __uint_as_float(rh << 16);
  uint v = __float_as_uint(r);
  l = (ushort)((v + 0x7FFFu + ((v >> 16) & 1u)) >> 16);
}

// ---------------------------------------------------------------------------
// Prep 1: elementwise split fp32 -> (H,L) bf16 planes (same layout).
// ---------------------------------------------------------------------------
__global__ __launch_bounds__(256) void split_k(
    const float* __restrict__ src, ushort* __restrict__ H, ushort* __restrict__ L)
{
  const int base = (blockIdx.x * 256 + threadIdx.x) * 16;
  float v[16];
  *(float4*)&v[0]  = *(const float4*)&src[base];
  *(float4*)&v[4]  = *(const float4*)&src[base + 4];
  *(float4*)&v[8]  = *(const float4*)&src[base + 8];
  *(float4*)&v[12] = *(const float4*)&src[base + 12];
  ushort hs[16], ls[16];
#pragma unroll
  for (int u = 0; u < 16; ++u) split2(v[u], hs[u], ls[u]);
  *(uint4*)&H[base]     = *(uint4*)&hs[0];
  *(uint4*)&H[base + 8] = *(uint4*)&hs[8];
  *(uint4*)&L[base]     = *(uint4*)&ls[0];
  *(uint4*)&L[base + 8] = *(uint4*)&ls[8];
}

// ---------------------------------------------------------------------------
// Prep 2: transpose + split for Wq/Wk:  WT[j][k] = W[k][j]  -> (H,L) planes.
// ---------------------------------------------------------------------------
__global__ __launch_bounds__(256) void splitT_k(
    const float* __restrict__ W0, const float* __restrict__ W1,
    ushort* __restrict__ H0, ushort* __restrict__ L0,
    ushort* __restrict__ H1, ushort* __restrict__ L1)
{
  const float* W = blockIdx.z ? W1 : W0;
  ushort* H = blockIdx.z ? H1 : H0;
  ushort* L = blockIdx.z ? L1 : L0;
  const int j0 = blockIdx.x * 64, k0 = blockIdx.y * 64;
  __shared__ float Tl[64][68];
  const int t = threadIdx.x, r = t >> 2, c = (t & 3) * 16;
#pragma unroll
  for (int u = 0; u < 4; ++u)
    *(float4*)&Tl[r][c + u * 4] = *(const float4*)&W[(k0 + r) * NN + j0 + c + u * 4];
  __syncthreads();
  ushort hs[16], ls[16];
#pragma unroll
  for (int u = 0; u < 16; ++u) split2(Tl[c + u][r], hs[u], ls[u]);
  const int ob = (j0 + r) * NN + k0 + c;
  *(uint4*)&H[ob]     = *(uint4*)&hs[0];
  *(uint4*)&H[ob + 8] = *(uint4*)&hs[8];
  *(uint4*)&L[ob]     = *(uint4*)&ls[0];
  *(uint4*)&L[ob + 8] = *(uint4*)&ls[8];
}

// ---------------------------------------------------------------------------
// Kernel 1 (MFMA): C = A @ B^T + bias ; A=roi planes, B = WT planes (NT).
// 128x128 tile, BK=32, 4 waves (2x2 of 64x64), 16x16x32 bf16, 3-product split.
// LDS frag-major: slot = frag*64 + (kc*16 + (row&15)); lane reads slot frag*64+lane.
// ---------------------------------------------------------------------------
__global__ __launch_bounds__(256) void gemm_qk_m(
    const ushort* __restrict__ AH, const ushort* __restrict__ AL,
    const ushort* __restrict__ B0H, const ushort* __restrict__ B0L,
    const ushort* __restrict__ B1H, const ushort* __restrict__ B1L,
    const float* __restrict__ b0, const float* __restrict__ b1,
    float* __restrict__ C0, float* __restrict__ C1)
{
  const ushort* BH = blockIdx.z ? B1H : B0H;
  const ushort* BL = blockIdx.z ? B1L : B0L;
  const float* bias = blockIdx.z ? b1 : b0;
  float* C = blockIdx.z ? C1 : C0;
  const int j0 = blockIdx.x * 128, i0 = blockIdx.y * 128;
  const int t = threadIdx.x, lane = t & 63, w = t >> 6;
  const int wr = w >> 1, wc = w & 1;

  __shared__ short8 sAH[512], sAL[512], sBH[512], sBL[512];

  const int kc = t & 3, r = t >> 2;
  const int slot0 = ((r >> 4) << 6) + (kc << 4) + (r & 15);
  const int slot1 = slot0 + 256;

  uint4 vah0, vah1, val0, val1, vbh0, vbh1, vbl0, vbl1;
#define LOADT(kt) { \
    const int ka = (kt) * 32 + (kc << 3); \
    vah0 = *(const uint4*)&AH[(i0 + r) * NN + ka]; \
    vah1 = *(const uint4*)&AH[(i0 + r + 64) * NN + ka]; \
    val0 = *(const uint4*)&AL[(i0 + r) * NN + ka]; \
    val1 = *(const uint4*)&AL[(i0 + r + 64) * NN + ka]; \
    vbh0 = *(const uint4*)&BH[(j0 + r) * NN + ka]; \
    vbh1 = *(const uint4*)&BH[(j0 + r + 64) * NN + ka]; \
    vbl0 = *(const uint4*)&BL[(j0 + r) * NN + ka]; \
    vbl1 = *(const uint4*)&BL[(j0 + r + 64) * NN + ka]; }

  LOADT(0);
  f32x4 acc[4][4] = {};

  for (int kt = 0; kt < 32; ++kt) {
    __syncthreads();
    *(uint4*)&sAH[slot0] = vah0; *(uint4*)&sAH[slot1] = vah1;
    *(uint4*)&sAL[slot0] = val0; *(uint4*)&sAL[slot1] = val1;
    *(uint4*)&sBH[slot0] = vbh0; *(uint4*)&sBH[slot1] = vbh1;
    *(uint4*)&sBL[slot0] = vbl0; *(uint4*)&sBL[slot1] = vbl1;
    __syncthreads();
    if (kt + 1 < 32) LOADT(kt + 1);
    short8 ah[4], al[4], bh[4], bl[4];
#pragma unroll
    for (int f = 0; f < 4; ++f) {
      ah[f] = sAH[(wr * 4 + f) * 64 + lane];
      al[f] = sAL[(wr * 4 + f) * 64 + lane];
      bh[f] = sBH[(wc * 4 + f) * 64 + lane];
      bl[f] = sBL[(wc * 4 + f) * 64 + lane];
    }
#pragma unroll
    for (int fm = 0; fm < 4; ++fm)
#pragma unroll
      for (int fn = 0; fn < 4; ++fn) {
        acc[fm][fn] = __builtin_amdgcn_mfma_f32_16x16x32_bf16(ah[fm], bh[fn], acc[fm][fn], 0, 0, 0);
        acc[fm][fn] = __builtin_amdgcn_mfma_f32_16x16x32_bf16(ah[fm], bl[fn], acc[fm][fn], 0, 0, 0);
        acc[fm][fn] = __builtin_amdgcn_mfma_f32_16x16x32_bf16(al[fm], bh[fn], acc[fm][fn], 0, 0, 0);
      }
  }
#undef LOADT

  const int crow = (lane >> 4) * 4, ccol = lane & 15;
#pragma unroll
  for (int fm = 0; fm < 4; ++fm) {
    const int row = i0 + wr * 64 + fm * 16 + crow;
#pragma unroll
    for (int fn = 0; fn < 4; ++fn) {
      const int col = j0 + wc * 64 + fn * 16 + ccol;
      const float bb = bias[col];
#pragma unroll
      for (int e = 0; e < 4; ++e)
        C[(row + e) * NN + col] = acc[fm][fn][e] + bb;
    }
  }
}

// ---------------------------------------------------------------------------
// Kernel 2 (MFMA): RW[g][j][kk] = sum_d roi[j][d] * Wc[g][kk][d]  (NT, batch g)
// 128x64 tile, BK=32, 4 waves (2x2 of 64x32), split 3-product.
// ---------------------------------------------------------------------------
__global__ __launch_bounds__(256) void gemm_rw_m(
    const ushort* __restrict__ AH, const ushort* __restrict__ AL,
    const ushort* __restrict__ WcH, const ushort* __restrict__ WcL,
    float* __restrict__ RW)
{
  const int g = blockIdx.y, j0 = blockIdx.x * 128;
  const int t = threadIdx.x, lane = t & 63, w = t >> 6;
  const int wr = w >> 1, wc = w & 1;
  const ushort* BH = WcH + (size_t)g * DGD * NN;
  const ushort* BL = WcL + (size_t)g * DGD * NN;

  __shared__ short8 sAH[512], sAL[512], sBH[256], sBL[256];

  const int kc = t & 3, r = t >> 2;
  const int slot0 = ((r >> 4) << 6) + (kc << 4) + (r & 15);
  const int slot1 = slot0 + 256;

  uint4 vah0, vah1, val0, val1, vbh, vbl;
#define LOADT(kt) { \
    const int ka = (kt) * 32 + (kc << 3); \
    vah0 = *(const uint4*)&AH[(j0 + r) * NN + ka]; \
    vah1 = *(const uint4*)&AH[(j0 + r + 64) * NN + ka]; \
    val0 = *(const uint4*)&AL[(j0 + r) * NN + ka]; \
    val1 = *(const uint4*)&AL[(j0 + r + 64) * NN + ka]; \
    vbh  = *(const uint4*)&BH[r * NN + ka]; \
    vbl  = *(const uint4*)&BL[r * NN + ka]; }

  LOADT(0);
  f32x4 acc[4][2] = {};

  for (int kt = 0; kt < 32; ++kt) {
    __syncthreads();
    *(uint4*)&sAH[slot0] = vah0; *(uint4*)&sAH[slot1] = vah1;
    *(uint4*)&sAL[slot0] = val0; *(uint4*)&sAL[slot1] = val1;
    *(uint4*)&sBH[slot0] = vbh;  *(uint4*)&sBL[slot0] = vbl;
    __syncthreads();
    if (kt + 1 < 32) LOADT(kt + 1);
    short8 ah[4], al[4], bh[2], bl[2];
#pragma unroll
    for (int f = 0; f < 4; ++f) {
      ah[f] = sAH[(wr * 4 + f) * 64 + lane];
      al[f] = sAL[(wr * 4 + f) * 64 + lane];
    }
#pragma unroll
    for (int f = 0; f < 2; ++f) {
      bh[f] = sBH[(wc * 2 + f) * 64 + lane];
      bl[f] = sBL[(wc * 2 + f) * 64 + lane];
    }
#pragma unroll
    for (int fm = 0; fm < 4; ++fm)
#pragma unroll
      for (int fn = 0; fn < 2; ++fn) {
        acc[fm][fn] = __builtin_amdgcn_mfma_f32_16x16x32_bf16(ah[fm], bh[fn], acc[fm][fn], 0, 0, 0);
        acc[fm][fn] = __builtin_amdgcn_mfma_f32_16x16x32_bf16(ah[fm], bl[fn], acc[fm][fn], 0, 0, 0);
        acc[fm][fn] = __builtin_amdgcn_mfma_f32_16x16x32_bf16(al[fm], bh[fn], acc[fm][fn], 0, 0, 0);
      }
  }
#undef LOADT

  const int crow = (lane >> 4) * 4, ccol = lane & 15;
  float* RWg = RW + (size_t)g * NN * DGD;
#pragma unroll
  for (int fm = 0; fm < 4; ++fm) {
    const int row = j0 + wr * 64 + fm * 16 + crow;
#pragma unroll
    for (int fn = 0; fn < 2; ++fn) {
      const int col = wc * 32 + fn * 16 + ccol;
#pragma unroll
      for (int e = 0; e < 4; ++e)
        RWg[(row + e) * DGD + col] = acc[fm][fn][e];
    }
  }
}

// ---------------------------------------------------------------------------
// Kernel 3: paff[i][g][j] = log(max(relu(emb(i,j)@W_pos + b_pos), 1e-6))
// ---------------------------------------------------------------------------
__global__ __launch_bounds__(256) void posaff_k(
    const float* __restrict__ bbox, const float* __restrict__ Wp,
    const float* __restrict__ bp, float* __restrict__ paff)
{
  const int i = blockIdx.y;
  const int j = blockIdx.x * 256 + threadIdx.x;

  __shared__ float WpS[1024];
  __shared__ float bpS[16];
  for (int u = threadIdx.x; u < 1024; u += 256) WpS[u] = Wp[u];
  if (threadIdx.x < 16) bpS[threadIdx.x] = bp[threadIdx.x];
  __syncthreads();

  const float xi0 = bbox[i*4+0], yi0 = bbox[i*4+1], xi1 = bbox[i*4+2], yi1 = bbox[i*4+3];
  const float wi = xi1 - xi0 + 1.0f, hi = yi1 - yi0 + 1.0f;
  const float cxi = 0.5f*(xi0+xi1), cyi = 0.5f*(yi0+yi1);
  const float xj0 = bbox[j*4+0], yj0 = bbox[j*4+1], xj1 = bbox[j*4+2], yj1 = bbox[j*4+3];
  const float wj = xj1 - xj0 + 1.0f, hj = yj1 - yj0 + 1.0f;
  const float cxj = 0.5f*(xj0+xj1), cyj = 0.5f*(yj0+yj1);

  float pos[4];
  pos[0] = __logf(fmaxf(fabsf((cxi - cxj) / wi), 1e-3f));
  pos[1] = __logf(fmaxf(fabsf((cyi - cyj) / hi), 1e-3f));
  pos[2] = __logf(fmaxf(fabsf(wi / wj), 1e-3f));
  pos[3] = __logf(fmaxf(fabsf(hi / hj), 1e-3f));

  const float invdim[8] = {1.0f, 0.42169650342858224f, 0.17782794100389228f,
      0.07498942093324558f, 0.03162277660168379f, 0.01333521432163324f,
      0.005623413251903491f, 0.0023713737056616554f};

  float acc[16];
#pragma unroll
  for (int g = 0; g < 16; ++g) acc[g] = bpS[g];

#pragma unroll
  for (int c = 0; c < 4; ++c) {
#pragma unroll
    for (int r = 0; r < 8; ++r) {
      float s, co;
      __sincosf(pos[c] * invdim[r], &s, &co);
      const float* w1 = &WpS[(c * 16 + r) * 16];
      const float* w2 = &WpS[(c * 16 + 8 + r) * 16];
#pragma unroll
      for (int g = 0; g < 16; ++g)
        acc[g] = fmaf(s, w1[g], fmaf(co, w2[g], acc[g]));
    }
  }
#pragma unroll
  for (int g = 0; g < 16; ++g)
    paff[((i * 16 + g) << 10) + j] = __logf(fmaxf(acc[g], 1e-6f));
}

// ---------------------------------------------------------------------------
// Kernel 4: flash attention, split-j (unchanged from R2).
// ---------------------------------------------------------------------------
__global__ __launch_bounds__(256) void attn_k(
    const float* __restrict__ q, const float* __restrict__ k,
    const float* __restrict__ RW, const float* __restrict__ paff,
    float* __restrict__ po, float* __restrict__ pstat)
{
  const int g  = blockIdx.y;
  const int i0 = blockIdx.x * 64;
  const int sp = blockIdx.z;
  const int t  = threadIdx.x;
  const int tx = t & 15, ty = t >> 4;

  __shared__ float QT[64][68];
  __shared__ float KRW[64][68];
  __shared__ float PT[64][68];

  const int sr = t >> 2;
  const int sc = (t & 3) * 16;

  {
    const float* qsrc = q + (i0 + sr) * NN + g * DGD + sc;
    float4 v0 = *(const float4*)&qsrc[0];
    float4 v1 = *(const float4*)&qsrc[4];
    float4 v2 = *(const float4*)&qsrc[8];
    float4 v3 = *(const float4*)&qsrc[12];
    float tv[16] = {v0.x,v0.y,v0.z,v0.w, v1.x,v1.y,v1.z,v1.w,
                    v2.x,v2.y,v2.z,v2.w, v3.x,v3.y,v3.z,v3.w};
#pragma unroll
    for (int u = 0; u < 16; ++u) QT[sc + u][sr] = tv[u];
  }

  float m[4], l[4], o[4][4];
#pragma unroll
  for (int im = 0; im < 4; ++im) {
    m[im] = -1e30f; l[im] = 0.f;
#pragma unroll
    for (int in = 0; in < 4; ++in) o[im][in] = 0.f;
  }

  const float* rwg = RW + (size_t)g * NN * DGD;

#pragma unroll 1
  for (int jt = sp * JT_PER; jt < sp * JT_PER + JT_PER; ++jt) {
    const int j0 = jt * 64;
    const float* ksrc = k + (j0 + sr) * NN + g * DGD + sc;
    float4 kv0 = *(const float4*)&ksrc[0];
    float4 kv1 = *(const float4*)&ksrc[4];
    float4 kv2 = *(const float4*)&ksrc[8];
    float4 kv3 = *(const float4*)&ksrc[12];
    const float* rsrc = rwg + (j0 + sr) * DGD + sc;
    float4 rv0 = *(const float4*)&rsrc[0];
    float4 rv1 = *(const float4*)&rsrc[4];
    float4 rv2 = *(const float4*)&rsrc[8];
    float4 rv3 = *(const float4*)&rsrc[12];
    float4 pf[4];
#pragma unroll
    for (int im = 0; im < 4; ++im)
      pf[im] = *(const float4*)&paff[(((i0 + ty * 4 + im) * GG + g) << 10) + j0 + tx * 4];

    __syncthreads();
    {
      float tv[16] = {kv0.x,kv0.y,kv0.z,kv0.w, kv1.x,kv1.y,kv1.z,kv1.w,
                      kv2.x,kv2.y,kv2.z,kv2.w, kv3.x,kv3.y,kv3.z,kv3.w};
#pragma unroll
      for (int u = 0; u < 16; ++u) KRW[sc + u][sr] = tv[u];
    }
    __syncthreads();

    float s[4][4] = {};
#pragma unroll 8
    for (int d = 0; d < 64; ++d) {
      float4 a = *(const float4*)&QT[d][ty * 4];
      float4 b = *(const float4*)&KRW[d][tx * 4];
      s[0][0] = fmaf(a.x, b.x, s[0][0]); s[0][1] = fmaf(a.x, b.y, s[0][1]);
      s[0][2] = fmaf(a.x, b.z, s[0][2]); s[0][3] = fmaf(a.x, b.w, s[0][3]);
      s[1][0] = fmaf(a.y, b.x, s[1][0]); s[1][1] = fmaf(a.y, b.y, s[1][1]);
      s[1][2] = fmaf(a.y, b.z, s[1][2]); s[1][3] = fmaf(a.y, b.w, s[1][3]);
      s[2][0] = fmaf(a.z, b.x, s[2][0]); s[2][1] = fmaf(a.z, b.y, s[2][1]);
      s[2][2] = fmaf(a.z, b.z, s[2][2]); s[2][3] = fmaf(a.z, b.w, s[2][3]);
      s[3][0] = fmaf(a.w, b.x, s[3][0]); s[3][1] = fmaf(a.w, b.y, s[3][1]);
      s[3][2] = fmaf(a.w, b.z, s[3][2]); s[3][3] = fmaf(a.w, b.w, s[3][3]);
    }

#pragma unroll
    for (int im = 0; im < 4; ++im) {
      float* pp = (float*)&pf[im];
      s[im][0] = fmaf(s[im][0], 0.125f, pp[0]);
      s[im][1] = fmaf(s[im][1], 0.125f, pp[1]);
      s[im][2] = fmaf(s[im][2], 0.125f, pp[2]);
      s[im][3] = fmaf(s[im][3], 0.125f, pp[3]);
      float tmax = fmaxf(fmaxf(s[im][0], s[im][1]), fmaxf(s[im][2], s[im][3]));
#pragma unroll
      for (int off = 1; off < 16; off <<= 1) tmax = fmaxf(tmax, __shfl_xor(tmax, off, 64));
      const float mnew = fmaxf(m[im], tmax);
      const float sc_  = __expf(m[im] - mnew);
      s[im][0] = __expf(s[im][0] - mnew);
      s[im][1] = __expf(s[im][1] - mnew);
      s[im][2] = __expf(s[im][2] - mnew);
      s[im][3] = __expf(s[im][3] - mnew);
      float tsum = (s[im][0] + s[im][1]) + (s[im][2] + s[im][3]);
#pragma unroll
      for (int off = 1; off < 16; off <<= 1) tsum += __shfl_xor(tsum, off, 64);
      l[im] = l[im] * sc_ + tsum;
      o[im][0] *= sc_; o[im][1] *= sc_; o[im][2] *= sc_; o[im][3] *= sc_;
      m[im] = mnew;
    }

    __syncthreads();
    *(float4*)&KRW[sr][sc + 0]  = rv0;
    *(float4*)&KRW[sr][sc + 4]  = rv1;
    *(float4*)&KRW[sr][sc + 8]  = rv2;
    *(float4*)&KRW[sr][sc + 12] = rv3;
#pragma unroll
    for (int jj = 0; jj < 4; ++jj) {
      float4 pv4; pv4.x = s[0][jj]; pv4.y = s[1][jj]; pv4.z = s[2][jj]; pv4.w = s[3][jj];
      *(float4*)&PT[tx * 4 + jj][ty * 4] = pv4;
    }
    __syncthreads();

#pragma unroll 8
    for (int j = 0; j < 64; ++j) {
      float4 a = *(const float4*)&PT[j][ty * 4];
      float4 b = *(const float4*)&KRW[j][tx * 4];
      o[0][0] = fmaf(a.x, b.x, o[0][0]); o[0][1] = fmaf(a.x, b.y, o[0][1]);
      o[0][2] = fmaf(a.x, b.z, o[0][2]); o[0][3] = fmaf(a.x, b.w, o[0][3]);
      o[1][0] = fmaf(a.y, b.x, o[1][0]); o[1][1] = fmaf(a.y, b.y, o[1][1]);
      o[1][2] = fmaf(a.y, b.z, o[1][2]); o[1][3] = fmaf(a.y, b.w, o[1][3]);
      o[2][0] = fmaf(a.z, b.x, o[2][0]); o[2][1] = fmaf(a.z, b.y, o[2][1]);
      o[2][2] = fmaf(a.z, b.z, o[2][2]); o[2][3] = fmaf(a.z, b.w, o[2][3]);
      o[3][0] = fmaf(a.w, b.x, o[3][0]); o[3][1] = fmaf(a.w, b.y, o[3][1]);
      o[3][2] = fmaf(a.w, b.z, o[3][2]); o[3][3] = fmaf(a.w, b.w, o[3][3]);
    }
  }

  const size_t idx = ((size_t)blockIdx.x * GG + g) * SPLIT + sp;
  float* pot = po + idx * 4096;
#pragma unroll
  for (int im = 0; im < 4; ++im) {
    float4 ov; ov.x = o[im][0]; ov.y = o[im][1]; ov.z = o[im][2]; ov.w = o[im][3];
    *(float4*)&pot[(ty * 4 + im) * 64 + tx * 4] = ov;
  }
  if (tx == 0) {
#pragma unroll
    for (int im = 0; im < 4; ++im) {
      float2 st; st.x = m[im]; st.y = l[im];
      *(float2*)&pstat[(idx * 64 + (ty * 4 + im)) * 2] = st;
    }
  }
}

// ---------------------------------------------------------------------------
// Kernel 4b: combine split partials -> res (+ residual + bias)
// ---------------------------------------------------------------------------
__global__ __launch_bounds__(256) void combine_k(
    const float* __restrict__ po, const float* __restrict__ pstat,
    const float* __restrict__ roi, const float* __restrict__ bconv,
    float* __restrict__ res)
{
  const int it = blockIdx.x, g = blockIdx.y;
  const int t = threadIdx.x;
  const int row = t >> 2, c0 = (t & 3) * 16;
  const size_t base = ((size_t)it * GG + g) * SPLIT;

  float ms[SPLIT], ls[SPLIT];
#pragma unroll
  for (int s = 0; s < SPLIT; ++s) {
    float2 st = *(const float2*)&pstat[((base + s) * 64 + row) * 2];
    ms[s] = st.x; ls[s] = st.y;
  }
  float M = fmaxf(fmaxf(ms[0], ms[1]), fmaxf(ms[2], ms[3]));
  float w[SPLIT], L = 0.f;
#pragma unroll
  for (int s = 0; s < SPLIT; ++s) { w[s] = __expf(ms[s] - M); L = fmaf(ls[s], w[s], L); }
  const float rL = 1.0f / L;

  const int grow = it * 64 + row;
  const int f0   = g * DGD + c0;
#pragma unroll
  for (int c = 0; c < 4; ++c) {
    float4 acc = {0.f, 0.f, 0.f, 0.f};
#pragma unroll
    for (int s = 0; s < SPLIT; ++s) {
      float4 v = *(const float4*)&po[(base + s) * 4096 + row * 64 + c0 + c * 4];
      acc.x = fmaf(v.x, w[s], acc.x);
      acc.y = fmaf(v.y, w[s], acc.y);
      acc.z = fmaf(v.z, w[s], acc.z);
      acc.w = fmaf(v.w, w[s], acc.w);
    }
    float4 r4 = *(const float4*)&roi[grow * NN + f0 + c * 4];
    float4 b4 = *(const float4*)&bconv[f0 + c * 4];
    float4 ov;
    ov.x = r4.x + b4.x + acc.x * rL;
    ov.y = r4.y + b4.y + acc.y * rL;
    ov.z = r4.z + b4.z + acc.z * rL;
    ov.w = r4.w + b4.w + acc.w * rL;
    *(float4*)&res[grow * NN + f0 + c * 4] = ov;
  }
}

// ---------------------------------------------------------------------------
// Kernel 5a: partial column sums of res
// ---------------------------------------------------------------------------
__global__ __launch_bounds__(256) void colsum_partial_k(
    const float* __restrict__ res, float* __restrict__ part)
{
  const int d  = blockIdx.x * 256 + threadIdx.x;
  const int r0 = blockIdx.y * 128;
  float s0 = 0.f, s1 = 0.f, s2 = 0.f, s3 = 0.f;
  for (int i = 0; i < 128; i += 4) {
    s0 += res[(r0 + i    ) * NN + d];
    s1 += res[(r0 + i + 1) * NN + d];
    s2 += res[(r0 + i + 2) * NN + d];
    s3 += res[(r0 + i + 3) * NN + d];
  }
  part[blockIdx.y * NN + d] = (s0 + s1) + (s2 + s3);
}

// ---------------------------------------------------------------------------
// Kernel 5b: reduce partials, logits = colsum@W_ro + b_ro, sigmoid.
// ---------------------------------------------------------------------------
__global__ __launch_bounds__(1024) void final_k(
    const float* __restrict__ part, const float* __restrict__ W_ro,
    const float* __restrict__ b_ro, float* __restrict__ out)
{
  __shared__ float cs[1024];
  const int t = threadIdx.x;
  float s = 0.f;
#pragma unroll
  for (int p = 0; p < 8; ++p) s += part[p * NN + t];
  cs[t] = s;
  __syncthreads();
  if (t < CLS) {
    float lg = b_ro[t];
    for (int d = 0; d < 1024; ++d) lg = fmaf(cs[d], W_ro[d * CLS + t], lg);
    out[t] = 1.0f / (1.0f + __expf(-lg));
  }
}

// ---------------------------------------------------------------------------
extern "C" void kernel_launch(void* const* d_in, const int* in_sizes, int n_in,
                              void* d_out, int out_size, void* d_ws, size_t ws_size,
                              hipStream_t stream) {
  const float* bbox  = (const float*)d_in[0];
  const float* roi   = (const float*)d_in[1];
  const float* W_pos = (const float*)d_in[2];
  const float* b_pos = (const float*)d_in[3];
  const float* Wq    = (const float*)d_in[4];
  const float* bq    = (const float*)d_in[5];
  const float* Wk    = (const float*)d_in[6];
  const float* bk    = (const float*)d_in[7];
  const float* Wc    = (const float*)d_in[8];
  const float* bcv   = (const float*)d_in[9];
  const float* W_ro  = (const float*)d_in[10];
  const float* b_ro  = (const float*)d_in[11];

  float* ws    = (float*)d_ws;
  float* q     = ws;                  // 1M floats
  float* kbuf  = ws + (1 << 20);      // 1M
  float* RW    = ws + (2 << 20);      // 1M
  float* res   = ws + (3 << 20);      // 1M
  float* part  = ws + (4 << 20);      // 8K
  float* paff  = ws + (5 << 20);      // 16M
  float* po    = ws + (21 << 20);     // 4M   (overlaps bf16 planes; disjoint lifetime)
  float* pstat = ws + (25 << 20);     // 128K

  // bf16 planes (live only until the GEMMs finish; po overwrites later)
  ushort* roiH = (ushort*)(ws + (21 << 20));
  ushort* roiL = (ushort*)(ws + (21 << 20) + (1 << 19));
  ushort* WqTH = (ushort*)(ws + (22 << 20));
  ushort* WqTL = (ushort*)(ws + (22 << 20) + (1 << 19));
  ushort* WkTH = (ushort*)(ws + (23 << 20));
  ushort* WkTL = (ushort*)(ws + (23 << 20) + (1 << 19));
  ushort* WcH  = (ushort*)(ws + (24 << 20));
  ushort* WcL  = (ushort*)(ws + (24 << 20) + (1 << 19));

  split_k<<<256, 256, 0, stream>>>(roi, roiH, roiL);
  split_k<<<256, 256, 0, stream>>>(Wc, WcH, WcL);
  splitT_k<<<dim3(16, 16, 2), 256, 0, stream>>>(Wq, Wk, WqTH, WqTL, WkTH, WkTL);

  gemm_qk_m<<<dim3(8, 8, 2), 256, 0, stream>>>(roiH, roiL, WqTH, WqTL, WkTH, WkTL,
                                               bq, bk, q, kbuf);
  gemm_rw_m<<<dim3(8, 16), 256, 0, stream>>>(roiH, roiL, WcH, WcL, RW);

  posaff_k<<<dim3(4, 1024), 256, 0, stream>>>(bbox, W_pos, b_pos, paff);
  attn_k<<<dim3(16, 16, SPLIT), 256, 0, stream>>>(q, kbuf, RW, paff, po, pstat);
  combine_k<<<dim3(16, 16), 256, 0, stream>>>(po, pstat, roi, bcv, res);
  colsum_partial_k<<<dim3(4, 8), 256, 0, stream>>>(res, part);
  final_k<<<1, 1024, 0, stream>>>(part, W_ro, b_ro, (float*)d_out);
}

// Round 5
// 216.748 us; speedup vs baseline: 2.0506x; 1.2290x over previous
//
#include <hip/hip_runtime.h>
#include <hip/hip_bf16.h>
#include <math.h>

#define NN   1024
#define GG   16
#define DGD  64
#define CLS  80
#define SPLIT 2
#define JT_PER 8   // 16 j-tiles / SPLIT

typedef __attribute__((ext_vector_type(8))) short short8;
typedef __attribute__((ext_vector_type(4))) float f32x4;

// bf16 split: x ~= hi + lo, each RNE-rounded bf16.
__device__ inline void split2(float x, ushort& h, ushort& l) {
  uint u = __float_as_uint(x);
  uint rh = (u + 0x7FFFu + ((u >> 16) & 1u)) >> 16;
  h = (ushort)rh;
  float r = x - __uint_as_float(rh << 16);
  uint v = __float_as_uint(r);
  l = (ushort)((v + 0x7FFFu + ((v >> 16) & 1u)) >> 16);
}

// frag-order LDS slot for a 64-row x 32-K half-tile (16B short8 units)
__device__ inline int lslot(int r, int kc) {
  return ((r >> 4) << 6) + (kc << 4) + (r & 15);
}

// ---------------------------------------------------------------------------
// Prep 1: elementwise split fp32 -> (H,L) bf16 planes.
// ---------------------------------------------------------------------------
__global__ __launch_bounds__(256) void split_k(
    const float* __restrict__ src, ushort* __restrict__ H, ushort* __restrict__ L)
{
  const int base = (blockIdx.x * 256 + threadIdx.x) * 16;
  float v[16];
  *(float4*)&v[0]  = *(const float4*)&src[base];
  *(float4*)&v[4]  = *(const float4*)&src[base + 4];
  *(float4*)&v[8]  = *(const float4*)&src[base + 8];
  *(float4*)&v[12] = *(const float4*)&src[base + 12];
  ushort hs[16], ls[16];
#pragma unroll
  for (int u = 0; u < 16; ++u) split2(v[u], hs[u], ls[u]);
  *(uint4*)&H[base]     = *(uint4*)&hs[0];
  *(uint4*)&H[base + 8] = *(uint4*)&hs[8];
  *(uint4*)&L[base]     = *(uint4*)&ls[0];
  *(uint4*)&L[base + 8] = *(uint4*)&ls[8];
}

// ---------------------------------------------------------------------------
// Prep 2: transpose + split for Wq/Wk: WT[j][k] = W[k][j] -> (H,L) planes.
// ---------------------------------------------------------------------------
__global__ __launch_bounds__(256) void splitT_k(
    const float* __restrict__ W0, const float* __restrict__ W1,
    ushort* __restrict__ H0, ushort* __restrict__ L0,
    ushort* __restrict__ H1, ushort* __restrict__ L1)
{
  const float* W = blockIdx.z ? W1 : W0;
  ushort* H = blockIdx.z ? H1 : H0;
  ushort* L = blockIdx.z ? L1 : L0;
  const int j0 = blockIdx.x * 64, k0 = blockIdx.y * 64;
  __shared__ float Tl[64][68];
  const int t = threadIdx.x, r = t >> 2, c = (t & 3) * 16;
#pragma unroll
  for (int u = 0; u < 4; ++u)
    *(float4*)&Tl[r][c + u * 4] = *(const float4*)&W[(k0 + r) * NN + j0 + c + u * 4];
  __syncthreads();
  ushort hs[16], ls[16];
#pragma unroll
  for (int u = 0; u < 16; ++u) split2(Tl[c + u][r], hs[u], ls[u]);
  const int ob = (j0 + r) * NN + k0 + c;
  *(uint4*)&H[ob]     = *(uint4*)&hs[0];
  *(uint4*)&H[ob + 8] = *(uint4*)&hs[8];
  *(uint4*)&L[ob]     = *(uint4*)&ls[0];
  *(uint4*)&L[ob + 8] = *(uint4*)&ls[8];
}

// ---------------------------------------------------------------------------
// Kernel 1 (MFMA): q/k = roi @ W^T + bias, written as split bf16 planes.
// 128x128 tile, BK=32, 4 waves (2x2 of 64x64), split 3-product.
// ---------------------------------------------------------------------------
__global__ __launch_bounds__(256) void gemm_qk_m(
    const ushort* __restrict__ AH, const ushort* __restrict__ AL,
    const ushort* __restrict__ B0H, const ushort* __restrict__ B0L,
    const ushort* __restrict__ B1H, const ushort* __restrict__ B1L,
    const float* __restrict__ b0, const float* __restrict__ b1,
    ushort* __restrict__ qhp, ushort* __restrict__ qlp,
    ushort* __restrict__ khp, ushort* __restrict__ klp)
{
  const ushort* BH = blockIdx.z ? B1H : B0H;
  const ushort* BL = blockIdx.z ? B1L : B0L;
  const float* bias = blockIdx.z ? b1 : b0;
  ushort* OH = blockIdx.z ? khp : qhp;
  ushort* OL = blockIdx.z ? klp : qlp;
  const int j0 = blockIdx.x * 128, i0 = blockIdx.y * 128;
  const int t = threadIdx.x, lane = t & 63, w = t >> 6;
  const int wr = w >> 1, wc = w & 1;

  __shared__ short8 sAH[512], sAL[512], sBH[512], sBL[512];

  const int kc = t & 3, r = t >> 2;
  const int slot0 = lslot(r, kc);
  const int slot1 = slot0 + 256;

  uint4 vah0, vah1, val0, val1, vbh0, vbh1, vbl0, vbl1;
#define LOADT(kt) { \
    const int ka = (kt) * 32 + (kc << 3); \
    vah0 = *(const uint4*)&AH[(i0 + r) * NN + ka]; \
    vah1 = *(const uint4*)&AH[(i0 + r + 64) * NN + ka]; \
    val0 = *(const uint4*)&AL[(i0 + r) * NN + ka]; \
    val1 = *(const uint4*)&AL[(i0 + r + 64) * NN + ka]; \
    vbh0 = *(const uint4*)&BH[(j0 + r) * NN + ka]; \
    vbh1 = *(const uint4*)&BH[(j0 + r + 64) * NN + ka]; \
    vbl0 = *(const uint4*)&BL[(j0 + r) * NN + ka]; \
    vbl1 = *(const uint4*)&BL[(j0 + r + 64) * NN + ka]; }

  LOADT(0);
  f32x4 acc[4][4] = {};

  for (int kt = 0; kt < 32; ++kt) {
    __syncthreads();
    *(uint4*)&sAH[slot0] = vah0; *(uint4*)&sAH[slot1] = vah1;
    *(uint4*)&sAL[slot0] = val0; *(uint4*)&sAL[slot1] = val1;
    *(uint4*)&sBH[slot0] = vbh0; *(uint4*)&sBH[slot1] = vbh1;
    *(uint4*)&sBL[slot0] = vbl0; *(uint4*)&sBL[slot1] = vbl1;
    __syncthreads();
    if (kt + 1 < 32) LOADT(kt + 1);
    short8 ah[4], al[4], bh[4], bl[4];
#pragma unroll
    for (int f = 0; f < 4; ++f) {
      ah[f] = sAH[(wr * 4 + f) * 64 + lane];
      al[f] = sAL[(wr * 4 + f) * 64 + lane];
      bh[f] = sBH[(wc * 4 + f) * 64 + lane];
      bl[f] = sBL[(wc * 4 + f) * 64 + lane];
    }
#pragma unroll
    for (int fm = 0; fm < 4; ++fm)
#pragma unroll
      for (int fn = 0; fn < 4; ++fn) {
        acc[fm][fn] = __builtin_amdgcn_mfma_f32_16x16x32_bf16(ah[fm], bh[fn], acc[fm][fn], 0, 0, 0);
        acc[fm][fn] = __builtin_amdgcn_mfma_f32_16x16x32_bf16(ah[fm], bl[fn], acc[fm][fn], 0, 0, 0);
        acc[fm][fn] = __builtin_amdgcn_mfma_f32_16x16x32_bf16(al[fm], bh[fn], acc[fm][fn], 0, 0, 0);
      }
  }
#undef LOADT

  const int crow = (lane >> 4) * 4, ccol = lane & 15;
#pragma unroll
  for (int fm = 0; fm < 4; ++fm) {
    const int row = i0 + wr * 64 + fm * 16 + crow;
#pragma unroll
    for (int fn = 0; fn < 4; ++fn) {
      const int col = j0 + wc * 64 + fn * 16 + ccol;
      const float bb = bias[col];
#pragma unroll
      for (int e = 0; e < 4; ++e) {
        float v = acc[fm][fn][e] + bb;
        ushort hh, ll; split2(v, hh, ll);
        OH[(size_t)(row + e) * NN + col] = hh;
        OL[(size_t)(row + e) * NN + col] = ll;
      }
    }
  }
}

// ---------------------------------------------------------------------------
// Kernel 2 (MFMA): RWT[g][kk][j] = sum_d Wc[g][kk][d] * roi[j][d]  (NT)
// M=kk(64), N=j(128 tile), BK=32, 4 waves (2x2 of 32x64). Split bf16 out.
// ---------------------------------------------------------------------------
__global__ __launch_bounds__(256) void gemm_rwt_m(
    const ushort* __restrict__ AH, const ushort* __restrict__ AL,   // Wc planes
    const ushort* __restrict__ BH, const ushort* __restrict__ BL,   // roi planes
    ushort* __restrict__ rwhp, ushort* __restrict__ rwlp)
{
  const int g = blockIdx.y, j0 = blockIdx.x * 128;
  const int t = threadIdx.x, lane = t & 63, w = t >> 6;
  const int wm = w >> 1, wn = w & 1;
  const ushort* AgH = AH + (size_t)g * DGD * NN;
  const ushort* AgL = AL + (size_t)g * DGD * NN;

  __shared__ short8 sAH[256], sAL[256], sBH[512], sBL[512];

  const int kc = t & 3, r = t >> 2;
  const int slot0 = lslot(r, kc);
  const int slot1 = slot0 + 256;

  uint4 vah, val, vbh0, vbh1, vbl0, vbl1;
#define LOADT(kt) { \
    const int ka = (kt) * 32 + (kc << 3); \
    vah  = *(const uint4*)&AgH[r * NN + ka]; \
    val  = *(const uint4*)&AgL[r * NN + ka]; \
    vbh0 = *(const uint4*)&BH[(j0 + r) * NN + ka]; \
    vbh1 = *(const uint4*)&BH[(j0 + r + 64) * NN + ka]; \
    vbl0 = *(const uint4*)&BL[(j0 + r) * NN + ka]; \
    vbl1 = *(const uint4*)&BL[(j0 + r + 64) * NN + ka]; }

  LOADT(0);
  f32x4 acc[2][4] = {};

  for (int kt = 0; kt < 32; ++kt) {
    __syncthreads();
    *(uint4*)&sAH[slot0] = vah;  *(uint4*)&sAL[slot0] = val;
    *(uint4*)&sBH[slot0] = vbh0; *(uint4*)&sBH[slot1] = vbh1;
    *(uint4*)&sBL[slot0] = vbl0; *(uint4*)&sBL[slot1] = vbl1;
    __syncthreads();
    if (kt + 1 < 32) LOADT(kt + 1);
    short8 ah[2], al[2], bh[4], bl[4];
#pragma unroll
    for (int f = 0; f < 2; ++f) {
      ah[f] = sAH[(wm * 2 + f) * 64 + lane];
      al[f] = sAL[(wm * 2 + f) * 64 + lane];
    }
#pragma unroll
    for (int f = 0; f < 4; ++f) {
      bh[f] = sBH[(wn * 4 + f) * 64 + lane];
      bl[f] = sBL[(wn * 4 + f) * 64 + lane];
    }
#pragma unroll
    for (int fm = 0; fm < 2; ++fm)
#pragma unroll
      for (int fn = 0; fn < 4; ++fn) {
        acc[fm][fn] = __builtin_amdgcn_mfma_f32_16x16x32_bf16(ah[fm], bh[fn], acc[fm][fn], 0, 0, 0);
        acc[fm][fn] = __builtin_amdgcn_mfma_f32_16x16x32_bf16(ah[fm], bl[fn], acc[fm][fn], 0, 0, 0);
        acc[fm][fn] = __builtin_amdgcn_mfma_f32_16x16x32_bf16(al[fm], bh[fn], acc[fm][fn], 0, 0, 0);
      }
  }
#undef LOADT

  const int crow = (lane >> 4) * 4, ccol = lane & 15;
#pragma unroll
  for (int fm = 0; fm < 2; ++fm) {
    const int row = wm * 32 + fm * 16 + crow;   // kk
#pragma unroll
    for (int fn = 0; fn < 4; ++fn) {
      const int col = j0 + wn * 64 + fn * 16 + ccol;   // j
#pragma unroll
      for (int e = 0; e < 4; ++e) {
        ushort hh, ll; split2(acc[fm][fn][e], hh, ll);
        rwhp[((size_t)g * DGD + row + e) * NN + col] = hh;
        rwlp[((size_t)g * DGD + row + e) * NN + col] = ll;
      }
    }
  }
}

// ---------------------------------------------------------------------------
// Kernel 3: paff = log(max(relu(emb@W_pos + b_pos), 1e-6)); 4 j per thread.
// ---------------------------------------------------------------------------
__global__ __launch_bounds__(256) void posaff_k(
    const float* __restrict__ bbox, const float* __restrict__ Wp,
    const float* __restrict__ bp, float* __restrict__ paff)
{
  const int i = blockIdx.x;
  const int t = threadIdx.x;
  const int j0 = t * 4;

  __shared__ float WpS[1024];
  __shared__ float bpS[16];
  for (int u = t; u < 1024; u += 256) WpS[u] = Wp[u];
  if (t < 16) bpS[t] = bp[t];
  __syncthreads();

  const float xi0 = bbox[i*4+0], yi0 = bbox[i*4+1], xi1 = bbox[i*4+2], yi1 = bbox[i*4+3];
  const float wi = xi1 - xi0 + 1.0f, hi = yi1 - yi0 + 1.0f;
  const float cxi = 0.5f*(xi0+xi1), cyi = 0.5f*(yi0+yi1);

  float pos[4][4];
#pragma unroll
  for (int jj = 0; jj < 4; ++jj) {
    float4 bj = *(const float4*)&bbox[(j0 + jj) * 4];
    const float wj = bj.z - bj.x + 1.0f, hj = bj.w - bj.y + 1.0f;
    const float cxj = 0.5f*(bj.x+bj.z), cyj = 0.5f*(bj.y+bj.w);
    pos[0][jj] = __logf(fmaxf(fabsf((cxi - cxj) / wi), 1e-3f));
    pos[1][jj] = __logf(fmaxf(fabsf((cyi - cyj) / hi), 1e-3f));
    pos[2][jj] = __logf(fmaxf(fabsf(wi / wj), 1e-3f));
    pos[3][jj] = __logf(fmaxf(fabsf(hi / hj), 1e-3f));
  }

  const float invdim[8] = {1.0f, 0.42169650342858224f, 0.17782794100389228f,
      0.07498942093324558f, 0.03162277660168379f, 0.01333521432163324f,
      0.005623413251903491f, 0.0023713737056616554f};

  float acc[16][4];
#pragma unroll
  for (int g = 0; g < 16; ++g)
#pragma unroll
    for (int jj = 0; jj < 4; ++jj) acc[g][jj] = bpS[g];

#pragma unroll
  for (int c = 0; c < 4; ++c) {
#pragma unroll
    for (int rr = 0; rr < 8; ++rr) {
      float sn[4], cs[4];
#pragma unroll
      for (int jj = 0; jj < 4; ++jj)
        __sincosf(pos[c][jj] * invdim[rr], &sn[jj], &cs[jj]);
      const float* w1 = &WpS[(c * 16 + rr) * 16];
      const float* w2 = &WpS[(c * 16 + 8 + rr) * 16];
#pragma unroll
      for (int g = 0; g < 16; ++g) {
        const float a1 = w1[g], a2 = w2[g];
#pragma unroll
        for (int jj = 0; jj < 4; ++jj)
          acc[g][jj] = fmaf(sn[jj], a1, fmaf(cs[jj], a2, acc[g][jj]));
      }
    }
  }
#pragma unroll
  for (int g = 0; g < 16; ++g) {
    float4 ov;
    ov.x = __logf(fmaxf(acc[g][0], 1e-6f));
    ov.y = __logf(fmaxf(acc[g][1], 1e-6f));
    ov.z = __logf(fmaxf(acc[g][2], 1e-6f));
    ov.w = __logf(fmaxf(acc[g][3], 1e-6f));
    *(float4*)&paff[((i * GG + g) << 10) + j0] = ov;
  }
}

// ---------------------------------------------------------------------------
// Kernel 4 (MFMA flash): block = 64 i-rows x g, SPLIT over j. Split-3 bf16
// for QK^T and PV; online softmax in C-frag registers (shfl over 16 lanes);
// P relayout via per-wave padded PT.
// ---------------------------------------------------------------------------
__global__ __launch_bounds__(256) void attn_m(
    const ushort* __restrict__ qhp, const ushort* __restrict__ qlp,
    const ushort* __restrict__ khp, const ushort* __restrict__ klp,
    const ushort* __restrict__ rwhp, const ushort* __restrict__ rwlp,
    const float* __restrict__ paff,
    float* __restrict__ po, float* __restrict__ pstat)
{
  const int g  = blockIdx.y;
  const int i0 = blockIdx.x * 64;
  const int sp = blockIdx.z;
  const int t  = threadIdx.x;
  const int lane = t & 63, w = t >> 6;

  __shared__ short8 sQH[512], sQL[512], sKH[512], sKL[512], sRH[512], sRL[512];
  __shared__ float PT[4][16][68];

  const int r  = t >> 2;
  const int kc = t & 3;
  const int sl = lslot(r, kc);

  // ---- stage Q (64 x 64, 2 K-halves x 2 planes) ----
  {
    const ushort* s0 = qhp + (size_t)(i0 + r) * NN + g * DGD + kc * 8;
    const ushort* s1 = qlp + (size_t)(i0 + r) * NN + g * DGD + kc * 8;
    *(uint4*)&sQH[sl]       = *(const uint4*)&s0[0];
    *(uint4*)&sQH[sl + 256] = *(const uint4*)&s0[32];
    *(uint4*)&sQL[sl]       = *(const uint4*)&s1[0];
    *(uint4*)&sQL[sl + 256] = *(const uint4*)&s1[32];
  }
  __syncthreads();
  const short8 qf_h0 = sQH[w * 64 + lane], qf_h1 = sQH[256 + w * 64 + lane];
  const short8 qf_l0 = sQL[w * 64 + lane], qf_l1 = sQL[256 + w * 64 + lane];

  const int qr = (lane >> 4) * 4;   // row base within frag
  const int qc = lane & 15;         // col within frag

  float m[4], l[4];
  f32x4 o[4] = {};
#pragma unroll
  for (int e = 0; e < 4; ++e) { m[e] = -1e30f; l[e] = 0.f; }

#pragma unroll 1
  for (int jt = sp * JT_PER; jt < sp * JT_PER + JT_PER; ++jt) {
    const int j0 = jt * 64;
    // global prefetch: K tile, RWT tile, paff frags
    const ushort* ks0 = khp + (size_t)(j0 + r) * NN + g * DGD + kc * 8;
    const ushort* ks1 = klp + (size_t)(j0 + r) * NN + g * DGD + kc * 8;
    uint4 kv00 = *(const uint4*)&ks0[0], kv01 = *(const uint4*)&ks0[32];
    uint4 kv10 = *(const uint4*)&ks1[0], kv11 = *(const uint4*)&ks1[32];
    const ushort* rs0 = rwhp + ((size_t)g * DGD + r) * NN + j0 + kc * 8;
    const ushort* rs1 = rwlp + ((size_t)g * DGD + r) * NN + j0 + kc * 8;
    uint4 rv00 = *(const uint4*)&rs0[0], rv01 = *(const uint4*)&rs0[32];
    uint4 rv10 = *(const uint4*)&rs1[0], rv11 = *(const uint4*)&rs1[32];
    float pf[4][4];
#pragma unroll
    for (int jf = 0; jf < 4; ++jf)
#pragma unroll
      for (int e = 0; e < 4; ++e)
        pf[jf][e] = paff[(((i0 + w * 16 + qr + e) * GG + g) << 10) + j0 + jf * 16 + qc];

    __syncthreads();   // A: prev iteration's MFMA reads done
    *(uint4*)&sKH[sl] = kv00; *(uint4*)&sKH[sl + 256] = kv01;
    *(uint4*)&sKL[sl] = kv10; *(uint4*)&sKL[sl + 256] = kv11;
    *(uint4*)&sRH[sl] = rv00; *(uint4*)&sRH[sl + 256] = rv01;
    *(uint4*)&sRL[sl] = rv10; *(uint4*)&sRL[sl + 256] = rv11;
    __syncthreads();   // B: tiles visible

    // ---- QK^T (split-3) ----
    f32x4 s4[4];
#pragma unroll
    for (int jf = 0; jf < 4; ++jf) {
      short8 bh0 = sKH[jf * 64 + lane], bh1 = sKH[256 + jf * 64 + lane];
      short8 bl0 = sKL[jf * 64 + lane], bl1 = sKL[256 + jf * 64 + lane];
      f32x4 a = {0.f, 0.f, 0.f, 0.f};
      a = __builtin_amdgcn_mfma_f32_16x16x32_bf16(qf_h0, bh0, a, 0, 0, 0);
      a = __builtin_amdgcn_mfma_f32_16x16x32_bf16(qf_h1, bh1, a, 0, 0, 0);
      a = __builtin_amdgcn_mfma_f32_16x16x32_bf16(qf_h0, bl0, a, 0, 0, 0);
      a = __builtin_amdgcn_mfma_f32_16x16x32_bf16(qf_h1, bl1, a, 0, 0, 0);
      a = __builtin_amdgcn_mfma_f32_16x16x32_bf16(qf_l0, bh0, a, 0, 0, 0);
      a = __builtin_amdgcn_mfma_f32_16x16x32_bf16(qf_l1, bh1, a, 0, 0, 0);
      s4[jf] = a;
    }

    // ---- online softmax (per row e, 16-lane groups) ----
#pragma unroll
    for (int e = 0; e < 4; ++e) {
      float v0 = fmaf(s4[0][e], 0.125f, pf[0][e]);
      float v1 = fmaf(s4[1][e], 0.125f, pf[1][e]);
      float v2 = fmaf(s4[2][e], 0.125f, pf[2][e]);
      float v3 = fmaf(s4[3][e], 0.125f, pf[3][e]);
      float tm = fmaxf(fmaxf(v0, v1), fmaxf(v2, v3));
#pragma unroll
      for (int off = 1; off < 16; off <<= 1) tm = fmaxf(tm, __shfl_xor(tm, off, 64));
      const float mn = fmaxf(m[e], tm);
      const float sc = __expf(m[e] - mn);
      v0 = __expf(v0 - mn); v1 = __expf(v1 - mn);
      v2 = __expf(v2 - mn); v3 = __expf(v3 - mn);
      float ts = (v0 + v1) + (v2 + v3);
#pragma unroll
      for (int off = 1; off < 16; off <<= 1) ts += __shfl_xor(ts, off, 64);
      l[e] = l[e] * sc + ts;
      m[e] = mn;
#pragma unroll
      for (int nf = 0; nf < 4; ++nf) o[nf][e] *= sc;
      PT[w][qr + e][ 0 + qc] = v0;
      PT[w][qr + e][16 + qc] = v1;
      PT[w][qr + e][32 + qc] = v2;
      PT[w][qr + e][48 + qc] = v3;
    }

    // ---- P frags (A-operand layout) + split ----
    short8 ph[2], pl[2];
#pragma unroll
    for (int h = 0; h < 2; ++h) {
      const float* psrc = &PT[w][lane & 15][h * 32 + (lane >> 4) * 8];
      float4 x = *(const float4*)&psrc[0];
      float4 y = *(const float4*)&psrc[4];
      float vv[8] = {x.x, x.y, x.z, x.w, y.x, y.y, y.z, y.w};
      ushort hh[8], ll[8];
#pragma unroll
      for (int u = 0; u < 8; ++u) split2(vv[u], hh[u], ll[u]);
      ph[h] = *(short8*)&hh[0];
      pl[h] = *(short8*)&ll[0];
    }

    // ---- PV (split-3) ----
#pragma unroll
    for (int nf = 0; nf < 4; ++nf) {
      short8 rh0 = sRH[nf * 64 + lane], rh1 = sRH[256 + nf * 64 + lane];
      short8 rl0 = sRL[nf * 64 + lane], rl1 = sRL[256 + nf * 64 + lane];
      f32x4 a = o[nf];
      a = __builtin_amdgcn_mfma_f32_16x16x32_bf16(ph[0], rh0, a, 0, 0, 0);
      a = __builtin_amdgcn_mfma_f32_16x16x32_bf16(ph[1], rh1, a, 0, 0, 0);
      a = __builtin_amdgcn_mfma_f32_16x16x32_bf16(ph[0], rl0, a, 0, 0, 0);
      a = __builtin_amdgcn_mfma_f32_16x16x32_bf16(ph[1], rl1, a, 0, 0, 0);
      a = __builtin_amdgcn_mfma_f32_16x16x32_bf16(pl[0], rh0, a, 0, 0, 0);
      a = __builtin_amdgcn_mfma_f32_16x16x32_bf16(pl[1], rh1, a, 0, 0, 0);
      o[nf] = a;
    }
  }

  // ---- epilogue: unnormalized partials + stats ----
  const size_t idx = ((size_t)blockIdx.x * GG + g) * SPLIT + sp;
  float* pot = po + idx * 4096;
#pragma unroll
  for (int nf = 0; nf < 4; ++nf)
#pragma unroll
    for (int e = 0; e < 4; ++e)
      pot[(w * 16 + qr + e) * 64 + nf * 16 + qc] = o[nf][e];
  if (qc == 0) {
#pragma unroll
    for (int e = 0; e < 4; ++e) {
      const int row = w * 16 + qr + e;
      pstat[(idx * 64 + row) * 2]     = m[e];
      pstat[(idx * 64 + row) * 2 + 1] = l[e];
    }
  }
}

// ---------------------------------------------------------------------------
// Kernel 4b: combine split partials -> res (+ residual + bias)
// ---------------------------------------------------------------------------
__global__ __launch_bounds__(256) void combine_k(
    const float* __restrict__ po, const float* __restrict__ pstat,
    const float* __restrict__ roi, const float* __restrict__ bconv,
    float* __restrict__ res)
{
  const int it = blockIdx.x, g = blockIdx.y;
  const int t = threadIdx.x;
  const int row = t >> 2, c0 = (t & 3) * 16;
  const size_t base = ((size_t)it * GG + g) * SPLIT;

  float ms[SPLIT], ls[SPLIT];
#pragma unroll
  for (int s = 0; s < SPLIT; ++s) {
    float2 st = *(const float2*)&pstat[((base + s) * 64 + row) * 2];
    ms[s] = st.x; ls[s] = st.y;
  }
  float M = ms[0];
#pragma unroll
  for (int s = 1; s < SPLIT; ++s) M = fmaxf(M, ms[s]);
  float wgt[SPLIT], L = 0.f;
#pragma unroll
  for (int s = 0; s < SPLIT; ++s) { wgt[s] = __expf(ms[s] - M); L = fmaf(ls[s], wgt[s], L); }
  const float rL = 1.0f / L;

  const int grow = it * 64 + row;
  const int f0   = g * DGD + c0;
#pragma unroll
  for (int c = 0; c < 4; ++c) {
    float4 acc = {0.f, 0.f, 0.f, 0.f};
#pragma unroll
    for (int s = 0; s < SPLIT; ++s) {
      float4 v = *(const float4*)&po[(base + s) * 4096 + row * 64 + c0 + c * 4];
      acc.x = fmaf(v.x, wgt[s], acc.x);
      acc.y = fmaf(v.y, wgt[s], acc.y);
      acc.z = fmaf(v.z, wgt[s], acc.z);
      acc.w = fmaf(v.w, wgt[s], acc.w);
    }
    float4 r4 = *(const float4*)&roi[grow * NN + f0 + c * 4];
    float4 b4 = *(const float4*)&bconv[f0 + c * 4];
    float4 ov;
    ov.x = r4.x + b4.x + acc.x * rL;
    ov.y = r4.y + b4.y + acc.y * rL;
    ov.z = r4.z + b4.z + acc.z * rL;
    ov.w = r4.w + b4.w + acc.w * rL;
    *(float4*)&res[grow * NN + f0 + c * 4] = ov;
  }
}

// ---------------------------------------------------------------------------
// Kernel 5a: partial column sums of res
// ---------------------------------------------------------------------------
__global__ __launch_bounds__(256) void colsum_partial_k(
    const float* __restrict__ res, float* __restrict__ part)
{
  const int d  = blockIdx.x * 256 + threadIdx.x;
  const int r0 = blockIdx.y * 128;
  float s0 = 0.f, s1 = 0.f, s2 = 0.f, s3 = 0.f;
  for (int i = 0; i < 128; i += 4) {
    s0 += res[(r0 + i    ) * NN + d];
    s1 += res[(r0 + i + 1) * NN + d];
    s2 += res[(r0 + i + 2) * NN + d];
    s3 += res[(r0 + i + 3) * NN + d];
  }
  part[blockIdx.y * NN + d] = (s0 + s1) + (s2 + s3);
}

// ---------------------------------------------------------------------------
// Kernel 5b: reduce partials, logits = colsum@W_ro + b_ro, sigmoid.
// ---------------------------------------------------------------------------
__global__ __launch_bounds__(1024) void final_k(
    const float* __restrict__ part, const float* __restrict__ W_ro,
    const float* __restrict__ b_ro, float* __restrict__ out)
{
  __shared__ float cs[1024];
  const int t = threadIdx.x;
  float s = 0.f;
#pragma unroll
  for (int p = 0; p < 8; ++p) s += part[p * NN + t];
  cs[t] = s;
  __syncthreads();
  if (t < CLS) {
    float lg = b_ro[t];
    for (int d = 0; d < 1024; ++d) lg = fmaf(cs[d], W_ro[d * CLS + t], lg);
    out[t] = 1.0f / (1.0f + __expf(-lg));
  }
}

// ---------------------------------------------------------------------------
extern "C" void kernel_launch(void* const* d_in, const int* in_sizes, int n_in,
                              void* d_out, int out_size, void* d_ws, size_t ws_size,
                              hipStream_t stream) {
  const float* bbox  = (const float*)d_in[0];
  const float* roi   = (const float*)d_in[1];
  const float* W_pos = (const float*)d_in[2];
  const float* b_pos = (const float*)d_in[3];
  const float* Wq    = (const float*)d_in[4];
  const float* bq    = (const float*)d_in[5];
  const float* Wk    = (const float*)d_in[6];
  const float* bk    = (const float*)d_in[7];
  const float* Wc    = (const float*)d_in[8];
  const float* bcv   = (const float*)d_in[9];
  const float* W_ro  = (const float*)d_in[10];
  const float* b_ro  = (const float*)d_in[11];

  float* ws = (float*)d_ws;
  // region A: paff lives posaff->attn
  float* paff = ws;                                     // 16M floats
  // region B: prep planes (dead after the two GEMMs)
  ushort* roiH = (ushort*)(ws + (16 << 20));
  ushort* roiL = (ushort*)(ws + (16 << 20) + (1 << 19));
  ushort* WqTH = (ushort*)(ws + (17 << 20));
  ushort* WqTL = (ushort*)(ws + (17 << 20) + (1 << 19));
  ushort* WkTH = (ushort*)(ws + (18 << 20));
  ushort* WkTL = (ushort*)(ws + (18 << 20) + (1 << 19));
  ushort* WcH  = (ushort*)(ws + (19 << 20));
  ushort* WcL  = (ushort*)(ws + (19 << 20) + (1 << 19));
  // region B reuse (attn outputs, written after preps are dead)
  float* po    = ws + (16 << 20);                       // 2M floats
  float* pstat = ws + (18 << 20);                       // 64K floats
  float* part  = ws + (18 << 20) + (1 << 18);           // 8K floats
  float* res   = ws + (19 << 20);                       // 1M floats
  // region C: split q/k/RWT planes (live gemm->attn)
  ushort* qHp  = (ushort*)(ws + (20 << 20));
  ushort* qLp  = (ushort*)(ws + (20 << 20) + (1 << 19));
  ushort* kHp  = (ushort*)(ws + (21 << 20));
  ushort* kLp  = (ushort*)(ws + (21 << 20) + (1 << 19));
  ushort* rwHp = (ushort*)(ws + (22 << 20));
  ushort* rwLp = (ushort*)(ws + (22 << 20) + (1 << 19));

  split_k<<<256, 256, 0, stream>>>(roi, roiH, roiL);
  split_k<<<256, 256, 0, stream>>>(Wc, WcH, WcL);
  splitT_k<<<dim3(16, 16, 2), 256, 0, stream>>>(Wq, Wk, WqTH, WqTL, WkTH, WkTL);

  gemm_qk_m<<<dim3(8, 8, 2), 256, 0, stream>>>(roiH, roiL, WqTH, WqTL, WkTH, WkTL,
                                               bq, bk, qHp, qLp, kHp, kLp);
  gemm_rwt_m<<<dim3(8, 16), 256, 0, stream>>>(WcH, WcL, roiH, roiL, rwHp, rwLp);

  posaff_k<<<1024, 256, 0, stream>>>(bbox, W_pos, b_pos, paff);
  attn_m<<<dim3(16, 16, SPLIT), 256, 0, stream>>>(qHp, qLp, kHp, kLp, rwHp, rwLp,
                                                  paff, po, pstat);
  combine_k<<<dim3(16, 16), 256, 0, stream>>>(po, pstat, roi, bcv, res);
  colsum_partial_k<<<dim3(4, 8), 256, 0, stream>>>(res, part);
  final_k<<<1, 1024, 0, stream>>>(part, W_ro, b_ro, (float*)d_out);
}

// Round 6
// 180.941 us; speedup vs baseline: 2.4563x; 1.1979x over previous
//
#include <hip/hip_runtime.h>
#include <hip/hip_bf16.h>
#include <math.h>

#define NN   1024
#define GG   16
#define DGD  64
#define CLS  80
#define SPLIT 2
#define JT_PER 8   // 16 j-tiles / SPLIT

typedef __attribute__((ext_vector_type(8))) short short8;
typedef __attribute__((ext_vector_type(4))) float f32x4;

// bf16 split: x ~= hi + lo, each RNE-rounded bf16.
__device__ inline void split2(float x, ushort& h, ushort& l) {
  uint u = __float_as_uint(x);
  uint rh = (u + 0x7FFFu + ((u >> 16) & 1u)) >> 16;
  h = (ushort)rh;
  float r = x - __uint_as_float(rh << 16);
  uint v = __float_as_uint(r);
  l = (ushort)((v + 0x7FFFu + ((v >> 16) & 1u)) >> 16);
}

// frag-order LDS slot for a 64-row x 32-K half-tile (16B short8 units)
__device__ inline int lslot(int r, int kc) {
  return ((r >> 4) << 6) + (kc << 4) + (r & 15);
}

// ---------------------------------------------------------------------------
// Prep 1: elementwise split fp32 -> (H,L) planes for roi (bid<256) and Wc.
// ---------------------------------------------------------------------------
__global__ __launch_bounds__(256) void split_k(
    const float* __restrict__ src0, ushort* __restrict__ H0, ushort* __restrict__ L0,
    const float* __restrict__ src1, ushort* __restrict__ H1, ushort* __restrict__ L1)
{
  const int bid = blockIdx.x;
  const float* src = bid < 256 ? src0 : src1;
  ushort* H = bid < 256 ? H0 : H1;
  ushort* L = bid < 256 ? L0 : L1;
  const int base = ((bid & 255) * 256 + threadIdx.x) * 16;
  float v[16];
  *(float4*)&v[0]  = *(const float4*)&src[base];
  *(float4*)&v[4]  = *(const float4*)&src[base + 4];
  *(float4*)&v[8]  = *(const float4*)&src[base + 8];
  *(float4*)&v[12] = *(const float4*)&src[base + 12];
  ushort hs[16], ls[16];
#pragma unroll
  for (int u = 0; u < 16; ++u) split2(v[u], hs[u], ls[u]);
  *(uint4*)&H[base]     = *(uint4*)&hs[0];
  *(uint4*)&H[base + 8] = *(uint4*)&hs[8];
  *(uint4*)&L[base]     = *(uint4*)&ls[0];
  *(uint4*)&L[base + 8] = *(uint4*)&ls[8];
}

// ---------------------------------------------------------------------------
// Prep 2: transpose + split for Wq/Wk: WT[j][k] = W[k][j] -> (H,L) planes.
// ---------------------------------------------------------------------------
__global__ __launch_bounds__(256) void splitT_k(
    const float* __restrict__ W0, const float* __restrict__ W1,
    ushort* __restrict__ H0, ushort* __restrict__ L0,
    ushort* __restrict__ H1, ushort* __restrict__ L1)
{
  const float* W = blockIdx.z ? W1 : W0;
  ushort* H = blockIdx.z ? H1 : H0;
  ushort* L = blockIdx.z ? L1 : L0;
  const int j0 = blockIdx.x * 64, k0 = blockIdx.y * 64;
  __shared__ float Tl[64][68];
  const int t = threadIdx.x, r = t >> 2, c = (t & 3) * 16;
#pragma unroll
  for (int u = 0; u < 4; ++u)
    *(float4*)&Tl[r][c + u * 4] = *(const float4*)&W[(k0 + r) * NN + j0 + c + u * 4];
  __syncthreads();
  ushort hs[16], ls[16];
#pragma unroll
  for (int u = 0; u < 16; ++u) split2(Tl[c + u][r], hs[u], ls[u]);
  const int ob = (j0 + r) * NN + k0 + c;
  *(uint4*)&H[ob]     = *(uint4*)&hs[0];
  *(uint4*)&H[ob + 8] = *(uint4*)&hs[8];
  *(uint4*)&L[ob]     = *(uint4*)&ls[0];
  *(uint4*)&L[ob + 8] = *(uint4*)&ls[8];
}

// ---------------------------------------------------------------------------
// Kernel 1 (MFMA): q/k = roi @ W^T + bias, written as split bf16 planes.
// ---------------------------------------------------------------------------
__global__ __launch_bounds__(256) void gemm_qk_m(
    const ushort* __restrict__ AH, const ushort* __restrict__ AL,
    const ushort* __restrict__ B0H, const ushort* __restrict__ B0L,
    const ushort* __restrict__ B1H, const ushort* __restrict__ B1L,
    const float* __restrict__ b0, const float* __restrict__ b1,
    ushort* __restrict__ qhp, ushort* __restrict__ qlp,
    ushort* __restrict__ khp, ushort* __restrict__ klp)
{
  const ushort* BH = blockIdx.z ? B1H : B0H;
  const ushort* BL = blockIdx.z ? B1L : B0L;
  const float* bias = blockIdx.z ? b1 : b0;
  ushort* OH = blockIdx.z ? khp : qhp;
  ushort* OL = blockIdx.z ? klp : qlp;
  const int j0 = blockIdx.x * 128, i0 = blockIdx.y * 128;
  const int t = threadIdx.x, lane = t & 63, w = t >> 6;
  const int wr = w >> 1, wc = w & 1;

  __shared__ short8 sAH[512], sAL[512], sBH[512], sBL[512];

  const int kc = t & 3, r = t >> 2;
  const int slot0 = lslot(r, kc);
  const int slot1 = slot0 + 256;

  uint4 vah0, vah1, val0, val1, vbh0, vbh1, vbl0, vbl1;
#define LOADT(kt) { \
    const int ka = (kt) * 32 + (kc << 3); \
    vah0 = *(const uint4*)&AH[(i0 + r) * NN + ka]; \
    vah1 = *(const uint4*)&AH[(i0 + r + 64) * NN + ka]; \
    val0 = *(const uint4*)&AL[(i0 + r) * NN + ka]; \
    val1 = *(const uint4*)&AL[(i0 + r + 64) * NN + ka]; \
    vbh0 = *(const uint4*)&BH[(j0 + r) * NN + ka]; \
    vbh1 = *(const uint4*)&BH[(j0 + r + 64) * NN + ka]; \
    vbl0 = *(const uint4*)&BL[(j0 + r) * NN + ka]; \
    vbl1 = *(const uint4*)&BL[(j0 + r + 64) * NN + ka]; }

  LOADT(0);
  f32x4 acc[4][4] = {};

  for (int kt = 0; kt < 32; ++kt) {
    __syncthreads();
    *(uint4*)&sAH[slot0] = vah0; *(uint4*)&sAH[slot1] = vah1;
    *(uint4*)&sAL[slot0] = val0; *(uint4*)&sAL[slot1] = val1;
    *(uint4*)&sBH[slot0] = vbh0; *(uint4*)&sBH[slot1] = vbh1;
    *(uint4*)&sBL[slot0] = vbl0; *(uint4*)&sBL[slot1] = vbl1;
    __syncthreads();
    if (kt + 1 < 32) LOADT(kt + 1);
    short8 ah[4], al[4], bh[4], bl[4];
#pragma unroll
    for (int f = 0; f < 4; ++f) {
      ah[f] = sAH[(wr * 4 + f) * 64 + lane];
      al[f] = sAL[(wr * 4 + f) * 64 + lane];
      bh[f] = sBH[(wc * 4 + f) * 64 + lane];
      bl[f] = sBL[(wc * 4 + f) * 64 + lane];
    }
#pragma unroll
    for (int fm = 0; fm < 4; ++fm)
#pragma unroll
      for (int fn = 0; fn < 4; ++fn) {
        acc[fm][fn] = __builtin_amdgcn_mfma_f32_16x16x32_bf16(ah[fm], bh[fn], acc[fm][fn], 0, 0, 0);
        acc[fm][fn] = __builtin_amdgcn_mfma_f32_16x16x32_bf16(ah[fm], bl[fn], acc[fm][fn], 0, 0, 0);
        acc[fm][fn] = __builtin_amdgcn_mfma_f32_16x16x32_bf16(al[fm], bh[fn], acc[fm][fn], 0, 0, 0);
      }
  }
#undef LOADT

  const int crow = (lane >> 4) * 4, ccol = lane & 15;
#pragma unroll
  for (int fm = 0; fm < 4; ++fm) {
    const int row = i0 + wr * 64 + fm * 16 + crow;
#pragma unroll
    for (int fn = 0; fn < 4; ++fn) {
      const int col = j0 + wc * 64 + fn * 16 + ccol;
      const float bb = bias[col];
#pragma unroll
      for (int e = 0; e < 4; ++e) {
        float v = acc[fm][fn][e] + bb;
        ushort hh, ll; split2(v, hh, ll);
        OH[(size_t)(row + e) * NN + col] = hh;
        OL[(size_t)(row + e) * NN + col] = ll;
      }
    }
  }
}

// ---------------------------------------------------------------------------
// Kernel 2 (MFMA): RWT[g][kk][j] = sum_d Wc[g][kk][d] * roi[j][d]  (NT)
// ---------------------------------------------------------------------------
__global__ __launch_bounds__(256) void gemm_rwt_m(
    const ushort* __restrict__ AH, const ushort* __restrict__ AL,   // Wc planes
    const ushort* __restrict__ BH, const ushort* __restrict__ BL,   // roi planes
    ushort* __restrict__ rwhp, ushort* __restrict__ rwlp)
{
  const int g = blockIdx.y, j0 = blockIdx.x * 128;
  const int t = threadIdx.x, lane = t & 63, w = t >> 6;
  const int wm = w >> 1, wn = w & 1;
  const ushort* AgH = AH + (size_t)g * DGD * NN;
  const ushort* AgL = AL + (size_t)g * DGD * NN;

  __shared__ short8 sAH[256], sAL[256], sBH[512], sBL[512];

  const int kc = t & 3, r = t >> 2;
  const int slot0 = lslot(r, kc);
  const int slot1 = slot0 + 256;

  uint4 vah, val, vbh0, vbh1, vbl0, vbl1;
#define LOADT(kt) { \
    const int ka = (kt) * 32 + (kc << 3); \
    vah  = *(const uint4*)&AgH[r * NN + ka]; \
    val  = *(const uint4*)&AgL[r * NN + ka]; \
    vbh0 = *(const uint4*)&BH[(j0 + r) * NN + ka]; \
    vbh1 = *(const uint4*)&BH[(j0 + r + 64) * NN + ka]; \
    vbl0 = *(const uint4*)&BL[(j0 + r) * NN + ka]; \
    vbl1 = *(const uint4*)&BL[(j0 + r + 64) * NN + ka]; }

  LOADT(0);
  f32x4 acc[2][4] = {};

  for (int kt = 0; kt < 32; ++kt) {
    __syncthreads();
    *(uint4*)&sAH[slot0] = vah;  *(uint4*)&sAL[slot0] = val;
    *(uint4*)&sBH[slot0] = vbh0; *(uint4*)&sBH[slot1] = vbh1;
    *(uint4*)&sBL[slot0] = vbl0; *(uint4*)&sBL[slot1] = vbl1;
    __syncthreads();
    if (kt + 1 < 32) LOADT(kt + 1);
    short8 ah[2], al[2], bh[4], bl[4];
#pragma unroll
    for (int f = 0; f < 2; ++f) {
      ah[f] = sAH[(wm * 2 + f) * 64 + lane];
      al[f] = sAL[(wm * 2 + f) * 64 + lane];
    }
#pragma unroll
    for (int f = 0; f < 4; ++f) {
      bh[f] = sBH[(wn * 4 + f) * 64 + lane];
      bl[f] = sBL[(wn * 4 + f) * 64 + lane];
    }
#pragma unroll
    for (int fm = 0; fm < 2; ++fm)
#pragma unroll
      for (int fn = 0; fn < 4; ++fn) {
        acc[fm][fn] = __builtin_amdgcn_mfma_f32_16x16x32_bf16(ah[fm], bh[fn], acc[fm][fn], 0, 0, 0);
        acc[fm][fn] = __builtin_amdgcn_mfma_f32_16x16x32_bf16(ah[fm], bl[fn], acc[fm][fn], 0, 0, 0);
        acc[fm][fn] = __builtin_amdgcn_mfma_f32_16x16x32_bf16(al[fm], bh[fn], acc[fm][fn], 0, 0, 0);
      }
  }
#undef LOADT

  const int crow = (lane >> 4) * 4, ccol = lane & 15;
#pragma unroll
  for (int fm = 0; fm < 2; ++fm) {
    const int row = wm * 32 + fm * 16 + crow;   // kk
#pragma unroll
    for (int fn = 0; fn < 4; ++fn) {
      const int col = j0 + wn * 64 + fn * 16 + ccol;   // j
#pragma unroll
      for (int e = 0; e < 4; ++e) {
        ushort hh, ll; split2(acc[fm][fn][e], hh, ll);
        rwhp[((size_t)g * DGD + row + e) * NN + col] = hh;
        rwlp[((size_t)g * DGD + row + e) * NN + col] = ll;
      }
    }
  }
}

// ---------------------------------------------------------------------------
// Kernel 3: paff = log(max(relu(emb@W_pos + b_pos), 1e-6)); 2 j per thread
// (4-j version spilled: acc[16][4] needs >80 VGPR, counter showed 60).
// ---------------------------------------------------------------------------
__global__ __launch_bounds__(256) void posaff_k(
    const float* __restrict__ bbox, const float* __restrict__ Wp,
    const float* __restrict__ bp, float* __restrict__ paff)
{
  const int i = blockIdx.y;
  const int t = threadIdx.x;
  const int j0 = (blockIdx.x * 256 + t) * 2;

  __shared__ float WpS[1024];
  __shared__ float bpS[16];
  for (int u = t; u < 1024; u += 256) WpS[u] = Wp[u];
  if (t < 16) bpS[t] = bp[t];
  __syncthreads();

  const float xi0 = bbox[i*4+0], yi0 = bbox[i*4+1], xi1 = bbox[i*4+2], yi1 = bbox[i*4+3];
  const float wi = xi1 - xi0 + 1.0f, hi = yi1 - yi0 + 1.0f;
  const float cxi = 0.5f*(xi0+xi1), cyi = 0.5f*(yi0+yi1);

  float pos[4][2];
#pragma unroll
  for (int jj = 0; jj < 2; ++jj) {
    float4 bj = *(const float4*)&bbox[(j0 + jj) * 4];
    const float wj = bj.z - bj.x + 1.0f, hj = bj.w - bj.y + 1.0f;
    const float cxj = 0.5f*(bj.x+bj.z), cyj = 0.5f*(bj.y+bj.w);
    pos[0][jj] = __logf(fmaxf(fabsf((cxi - cxj) / wi), 1e-3f));
    pos[1][jj] = __logf(fmaxf(fabsf((cyi - cyj) / hi), 1e-3f));
    pos[2][jj] = __logf(fmaxf(fabsf(wi / wj), 1e-3f));
    pos[3][jj] = __logf(fmaxf(fabsf(hi / hj), 1e-3f));
  }

  const float invdim[8] = {1.0f, 0.42169650342858224f, 0.17782794100389228f,
      0.07498942093324558f, 0.03162277660168379f, 0.01333521432163324f,
      0.005623413251903491f, 0.0023713737056616554f};

  float acc[16][2];
#pragma unroll
  for (int g = 0; g < 16; ++g) { acc[g][0] = bpS[g]; acc[g][1] = bpS[g]; }

#pragma unroll
  for (int c = 0; c < 4; ++c) {
#pragma unroll
    for (int rr = 0; rr < 8; ++rr) {
      float sn0, cs0, sn1, cs1;
      __sincosf(pos[c][0] * invdim[rr], &sn0, &cs0);
      __sincosf(pos[c][1] * invdim[rr], &sn1, &cs1);
      const float* w1 = &WpS[(c * 16 + rr) * 16];
      const float* w2 = &WpS[(c * 16 + 8 + rr) * 16];
#pragma unroll
      for (int g = 0; g < 16; ++g) {
        const float a1 = w1[g], a2 = w2[g];
        acc[g][0] = fmaf(sn0, a1, fmaf(cs0, a2, acc[g][0]));
        acc[g][1] = fmaf(sn1, a1, fmaf(cs1, a2, acc[g][1]));
      }
    }
  }
#pragma unroll
  for (int g = 0; g < 16; ++g) {
    float2 ov;
    ov.x = __logf(fmaxf(acc[g][0], 1e-6f));
    ov.y = __logf(fmaxf(acc[g][1], 1e-6f));
    *(float2*)&paff[((i * GG + g) << 10) + j0] = ov;
  }
}

// ---------------------------------------------------------------------------
// Kernel 4 (MFMA flash): block = 64 i-rows x g, SPLIT over j.
// ---------------------------------------------------------------------------
__global__ __launch_bounds__(256) void attn_m(
    const ushort* __restrict__ qhp, const ushort* __restrict__ qlp,
    const ushort* __restrict__ khp, const ushort* __restrict__ klp,
    const ushort* __restrict__ rwhp, const ushort* __restrict__ rwlp,
    const float* __restrict__ paff,
    float* __restrict__ po, float* __restrict__ pstat)
{
  const int g  = blockIdx.y;
  const int i0 = blockIdx.x * 64;
  const int sp = blockIdx.z;
  const int t  = threadIdx.x;
  const int lane = t & 63, w = t >> 6;

  __shared__ short8 sQH[512], sQL[512], sKH[512], sKL[512], sRH[512], sRL[512];
  __shared__ float PT[4][16][68];

  const int r  = t >> 2;
  const int kc = t & 3;
  const int sl = lslot(r, kc);

  // ---- stage Q (64 x 64, 2 K-halves x 2 planes) ----
  {
    const ushort* s0 = qhp + (size_t)(i0 + r) * NN + g * DGD + kc * 8;
    const ushort* s1 = qlp + (size_t)(i0 + r) * NN + g * DGD + kc * 8;
    *(uint4*)&sQH[sl]       = *(const uint4*)&s0[0];
    *(uint4*)&sQH[sl + 256] = *(const uint4*)&s0[32];
    *(uint4*)&sQL[sl]       = *(const uint4*)&s1[0];
    *(uint4*)&sQL[sl + 256] = *(const uint4*)&s1[32];
  }
  __syncthreads();
  const short8 qf_h0 = sQH[w * 64 + lane], qf_h1 = sQH[256 + w * 64 + lane];
  const short8 qf_l0 = sQL[w * 64 + lane], qf_l1 = sQL[256 + w * 64 + lane];

  const int qr = (lane >> 4) * 4;   // row base within frag
  const int qc = lane & 15;         // col within frag

  float m[4], l[4];
  f32x4 o[4] = {};
#pragma unroll
  for (int e = 0; e < 4; ++e) { m[e] = -1e30f; l[e] = 0.f; }

#pragma unroll 1
  for (int jt = sp * JT_PER; jt < sp * JT_PER + JT_PER; ++jt) {
    const int j0 = jt * 64;
    const ushort* ks0 = khp + (size_t)(j0 + r) * NN + g * DGD + kc * 8;
    const ushort* ks1 = klp + (size_t)(j0 + r) * NN + g * DGD + kc * 8;
    uint4 kv00 = *(const uint4*)&ks0[0], kv01 = *(const uint4*)&ks0[32];
    uint4 kv10 = *(const uint4*)&ks1[0], kv11 = *(const uint4*)&ks1[32];
    const ushort* rs0 = rwhp + ((size_t)g * DGD + r) * NN + j0 + kc * 8;
    const ushort* rs1 = rwlp + ((size_t)g * DGD + r) * NN + j0 + kc * 8;
    uint4 rv00 = *(const uint4*)&rs0[0], rv01 = *(const uint4*)&rs0[32];
    uint4 rv10 = *(const uint4*)&rs1[0], rv11 = *(const uint4*)&rs1[32];
    float pf[4][4];
#pragma unroll
    for (int jf = 0; jf < 4; ++jf)
#pragma unroll
      for (int e = 0; e < 4; ++e)
        pf[jf][e] = paff[(((i0 + w * 16 + qr + e) * GG + g) << 10) + j0 + jf * 16 + qc];

    __syncthreads();   // A: prev iteration's MFMA reads done
    *(uint4*)&sKH[sl] = kv00; *(uint4*)&sKH[sl + 256] = kv01;
    *(uint4*)&sKL[sl] = kv10; *(uint4*)&sKL[sl + 256] = kv11;
    *(uint4*)&sRH[sl] = rv00; *(uint4*)&sRH[sl + 256] = rv01;
    *(uint4*)&sRL[sl] = rv10; *(uint4*)&sRL[sl + 256] = rv11;
    __syncthreads();   // B: tiles visible

    // ---- QK^T (split-3) ----
    f32x4 s4[4];
#pragma unroll
    for (int jf = 0; jf < 4; ++jf) {
      short8 bh0 = sKH[jf * 64 + lane], bh1 = sKH[256 + jf * 64 + lane];
      short8 bl0 = sKL[jf * 64 + lane], bl1 = sKL[256 + jf * 64 + lane];
      f32x4 a = {0.f, 0.f, 0.f, 0.f};
      a = __builtin_amdgcn_mfma_f32_16x16x32_bf16(qf_h0, bh0, a, 0, 0, 0);
      a = __builtin_amdgcn_mfma_f32_16x16x32_bf16(qf_h1, bh1, a, 0, 0, 0);
      a = __builtin_amdgcn_mfma_f32_16x16x32_bf16(qf_h0, bl0, a, 0, 0, 0);
      a = __builtin_amdgcn_mfma_f32_16x16x32_bf16(qf_h1, bl1, a, 0, 0, 0);
      a = __builtin_amdgcn_mfma_f32_16x16x32_bf16(qf_l0, bh0, a, 0, 0, 0);
      a = __builtin_amdgcn_mfma_f32_16x16x32_bf16(qf_l1, bh1, a, 0, 0, 0);
      s4[jf] = a;
    }

    // ---- online softmax (per row e, 16-lane groups) ----
#pragma unroll
    for (int e = 0; e < 4; ++e) {
      float v0 = fmaf(s4[0][e], 0.125f, pf[0][e]);
      float v1 = fmaf(s4[1][e], 0.125f, pf[1][e]);
      float v2 = fmaf(s4[2][e], 0.125f, pf[2][e]);
      float v3 = fmaf(s4[3][e], 0.125f, pf[3][e]);
      float tm = fmaxf(fmaxf(v0, v1), fmaxf(v2, v3));
#pragma unroll
      for (int off = 1; off < 16; off <<= 1) tm = fmaxf(tm, __shfl_xor(tm, off, 64));
      const float mn = fmaxf(m[e], tm);
      const float sc = __expf(m[e] - mn);
      v0 = __expf(v0 - mn); v1 = __expf(v1 - mn);
      v2 = __expf(v2 - mn); v3 = __expf(v3 - mn);
      float ts = (v0 + v1) + (v2 + v3);
#pragma unroll
      for (int off = 1; off < 16; off <<= 1) ts += __shfl_xor(ts, off, 64);
      l[e] = l[e] * sc + ts;
      m[e] = mn;
#pragma unroll
      for (int nf = 0; nf < 4; ++nf) o[nf][e] *= sc;
      PT[w][qr + e][ 0 + qc] = v0;
      PT[w][qr + e][16 + qc] = v1;
      PT[w][qr + e][32 + qc] = v2;
      PT[w][qr + e][48 + qc] = v3;
    }

    // ---- P frags (A-operand layout) + split ----
    short8 ph[2], pl[2];
#pragma unroll
    for (int h = 0; h < 2; ++h) {
      const float* psrc = &PT[w][lane & 15][h * 32 + (lane >> 4) * 8];
      float4 x = *(const float4*)&psrc[0];
      float4 y = *(const float4*)&psrc[4];
      float vv[8] = {x.x, x.y, x.z, x.w, y.x, y.y, y.z, y.w};
      ushort hh[8], ll[8];
#pragma unroll
      for (int u = 0; u < 8; ++u) split2(vv[u], hh[u], ll[u]);
      ph[h] = *(short8*)&hh[0];
      pl[h] = *(short8*)&ll[0];
    }

    // ---- PV (split-3) ----
#pragma unroll
    for (int nf = 0; nf < 4; ++nf) {
      short8 rh0 = sRH[nf * 64 + lane], rh1 = sRH[256 + nf * 64 + lane];
      short8 rl0 = sRL[nf * 64 + lane], rl1 = sRL[256 + nf * 64 + lane];
      f32x4 a = o[nf];
      a = __builtin_amdgcn_mfma_f32_16x16x32_bf16(ph[0], rh0, a, 0, 0, 0);
      a = __builtin_amdgcn_mfma_f32_16x16x32_bf16(ph[1], rh1, a, 0, 0, 0);
      a = __builtin_amdgcn_mfma_f32_16x16x32_bf16(ph[0], rl0, a, 0, 0, 0);
      a = __builtin_amdgcn_mfma_f32_16x16x32_bf16(ph[1], rl1, a, 0, 0, 0);
      a = __builtin_amdgcn_mfma_f32_16x16x32_bf16(pl[0], rh0, a, 0, 0, 0);
      a = __builtin_amdgcn_mfma_f32_16x16x32_bf16(pl[1], rh1, a, 0, 0, 0);
      o[nf] = a;
    }
  }

  // ---- epilogue: unnormalized partials + stats ----
  const size_t idx = ((size_t)blockIdx.x * GG + g) * SPLIT + sp;
  float* pot = po + idx * 4096;
#pragma unroll
  for (int nf = 0; nf < 4; ++nf)
#pragma unroll
    for (int e = 0; e < 4; ++e)
      pot[(w * 16 + qr + e) * 64 + nf * 16 + qc] = o[nf][e];
  if (qc == 0) {
#pragma unroll
    for (int e = 0; e < 4; ++e) {
      const int row = w * 16 + qr + e;
      pstat[(idx * 64 + row) * 2]     = m[e];
      pstat[(idx * 64 + row) * 2 + 1] = l[e];
    }
  }
}

// ---------------------------------------------------------------------------
// Kernel 4b: combine split partials -> res (+ residual + bias)
// ---------------------------------------------------------------------------
__global__ __launch_bounds__(256) void combine_k(
    const float* __restrict__ po, const float* __restrict__ pstat,
    const float* __restrict__ roi, const float* __restrict__ bconv,
    float* __restrict__ res)
{
  const int it = blockIdx.x, g = blockIdx.y;
  const int t = threadIdx.x;
  const int row = t >> 2, c0 = (t & 3) * 16;
  const size_t base = ((size_t)it * GG + g) * SPLIT;

  float ms[SPLIT], ls[SPLIT];
#pragma unroll
  for (int s = 0; s < SPLIT; ++s) {
    float2 st = *(const float2*)&pstat[((base + s) * 64 + row) * 2];
    ms[s] = st.x; ls[s] = st.y;
  }
  float M = ms[0];
#pragma unroll
  for (int s = 1; s < SPLIT; ++s) M = fmaxf(M, ms[s]);
  float wgt[SPLIT], L = 0.f;
#pragma unroll
  for (int s = 0; s < SPLIT; ++s) { wgt[s] = __expf(ms[s] - M); L = fmaf(ls[s], wgt[s], L); }
  const float rL = 1.0f / L;

  const int grow = it * 64 + row;
  const int f0   = g * DGD + c0;
#pragma unroll
  for (int c = 0; c < 4; ++c) {
    float4 acc = {0.f, 0.f, 0.f, 0.f};
#pragma unroll
    for (int s = 0; s < SPLIT; ++s) {
      float4 v = *(const float4*)&po[(base + s) * 4096 + row * 64 + c0 + c * 4];
      acc.x = fmaf(v.x, wgt[s], acc.x);
      acc.y = fmaf(v.y, wgt[s], acc.y);
      acc.z = fmaf(v.z, wgt[s], acc.z);
      acc.w = fmaf(v.w, wgt[s], acc.w);
    }
    float4 r4 = *(const float4*)&roi[grow * NN + f0 + c * 4];
    float4 b4 = *(const float4*)&bconv[f0 + c * 4];
    float4 ov;
    ov.x = r4.x + b4.x + acc.x * rL;
    ov.y = r4.y + b4.y + acc.y * rL;
    ov.z = r4.z + b4.z + acc.z * rL;
    ov.w = r4.w + b4.w + acc.w * rL;
    *(float4*)&res[grow * NN + f0 + c * 4] = ov;
  }
}

// ---------------------------------------------------------------------------
// Kernel 5a: partial column sums of res
// ---------------------------------------------------------------------------
__global__ __launch_bounds__(256) void colsum_partial_k(
    const float* __restrict__ res, float* __restrict__ part)
{
  const int d  = blockIdx.x * 256 + threadIdx.x;
  const int r0 = blockIdx.y * 128;
  float s0 = 0.f, s1 = 0.f, s2 = 0.f, s3 = 0.f;
  for (int i = 0; i < 128; i += 4) {
    s0 += res[(r0 + i    ) * NN + d];
    s1 += res[(r0 + i + 1) * NN + d];
    s2 += res[(r0 + i + 2) * NN + d];
    s3 += res[(r0 + i + 3) * NN + d];
  }
  part[blockIdx.y * NN + d] = (s0 + s1) + (s2 + s3);
}

// ---------------------------------------------------------------------------
// Kernel 5b: reduce partials, logits = colsum@W_ro + b_ro, sigmoid.
// 640 threads: t = s*80+c; 8-way d-split per class, LDS reduce.
// (old version: 80 threads, 1024-long dependent load chain = 63 us)
// ---------------------------------------------------------------------------
__global__ __launch_bounds__(640) void final_k(
    const float* __restrict__ part, const float* __restrict__ W_ro,
    const float* __restrict__ b_ro, float* __restrict__ out)
{
  __shared__ float cs[1024];
  __shared__ float red[8][CLS];
  const int t = threadIdx.x;

  for (int u = t; u < 1024; u += 640) {
    float s = 0.f;
#pragma unroll
    for (int p = 0; p < 8; ++p) s += part[p * NN + u];
    cs[u] = s;
  }
  __syncthreads();

  {
    const int c = t % CLS, s = t / CLS;   // s in 0..7
    float acc = 0.f;
    const int d0 = s * 128;
#pragma unroll 8
    for (int d = d0; d < d0 + 128; ++d)
      acc = fmaf(cs[d], W_ro[d * CLS + c], acc);
    red[s][c] = acc;
  }
  __syncthreads();

  if (t < CLS) {
    float lg = b_ro[t];
#pragma unroll
    for (int s = 0; s < 8; ++s) lg += red[s][t];
    out[t] = 1.0f / (1.0f + __expf(-lg));
  }
}

// ---------------------------------------------------------------------------
extern "C" void kernel_launch(void* const* d_in, const int* in_sizes, int n_in,
                              void* d_out, int out_size, void* d_ws, size_t ws_size,
                              hipStream_t stream) {
  const float* bbox  = (const float*)d_in[0];
  const float* roi   = (const float*)d_in[1];
  const float* W_pos = (const float*)d_in[2];
  const float* b_pos = (const float*)d_in[3];
  const float* Wq    = (const float*)d_in[4];
  const float* bq    = (const float*)d_in[5];
  const float* Wk    = (const float*)d_in[6];
  const float* bk    = (const float*)d_in[7];
  const float* Wc    = (const float*)d_in[8];
  const float* bcv   = (const float*)d_in[9];
  const float* W_ro  = (const float*)d_in[10];
  const float* b_ro  = (const float*)d_in[11];

  float* ws = (float*)d_ws;
  // region A: paff lives posaff->attn
  float* paff = ws;                                     // 16M floats
  // region B: prep planes (dead after the two GEMMs)
  ushort* roiH = (ushort*)(ws + (16 << 20));
  ushort* roiL = (ushort*)(ws + (16 << 20) + (1 << 19));
  ushort* WqTH = (ushort*)(ws + (17 << 20));
  ushort* WqTL = (ushort*)(ws + (17 << 20) + (1 << 19));
  ushort* WkTH = (ushort*)(ws + (18 << 20));
  ushort* WkTL = (ushort*)(ws + (18 << 20) + (1 << 19));
  ushort* WcH  = (ushort*)(ws + (19 << 20));
  ushort* WcL  = (ushort*)(ws + (19 << 20) + (1 << 19));
  // region B reuse (attn outputs, written after preps are dead)
  float* po    = ws + (16 << 20);                       // 2M floats
  float* pstat = ws + (18 << 20);                       // 64K floats
  float* part  = ws + (18 << 20) + (1 << 18);           // 8K floats
  float* res   = ws + (19 << 20);                       // 1M floats
  // region C: split q/k/RWT planes (live gemm->attn)
  ushort* qHp  = (ushort*)(ws + (20 << 20));
  ushort* qLp  = (ushort*)(ws + (20 << 20) + (1 << 19));
  ushort* kHp  = (ushort*)(ws + (21 << 20));
  ushort* kLp  = (ushort*)(ws + (21 << 20) + (1 << 19));
  ushort* rwHp = (ushort*)(ws + (22 << 20));
  ushort* rwLp = (ushort*)(ws + (22 << 20) + (1 << 19));

  split_k<<<512, 256, 0, stream>>>(roi, roiH, roiL, Wc, WcH, WcL);
  splitT_k<<<dim3(16, 16, 2), 256, 0, stream>>>(Wq, Wk, WqTH, WqTL, WkTH, WkTL);

  gemm_qk_m<<<dim3(8, 8, 2), 256, 0, stream>>>(roiH, roiL, WqTH, WqTL, WkTH, WkTL,
                                               bq, bk, qHp, qLp, kHp, kLp);
  gemm_rwt_m<<<dim3(8, 16), 256, 0, stream>>>(WcH, WcL, roiH, roiL, rwHp, rwLp);

  posaff_k<<<dim3(2, 1024), 256, 0, stream>>>(bbox, W_pos, b_pos, paff);
  attn_m<<<dim3(16, 16, SPLIT), 256, 0, stream>>>(qHp, qLp, kHp, kLp, rwHp, rwLp,
                                                  paff, po, pstat);
  combine_k<<<dim3(16, 16), 256, 0, stream>>>(po, pstat, roi, bcv, res);
  colsum_partial_k<<<dim3(4, 8), 256, 0, stream>>>(res, part);
  final_k<<<1, 640, 0, stream>>>(part, W_ro, b_ro, (float*)d_out);
}

// Round 7
// 180.833 us; speedup vs baseline: 2.4578x; 1.0006x over previous
//
#include <hip/hip_runtime.h>
#include <hip/hip_bf16.h>
#include <math.h>

#define NN   1024
#define GG   16
#define DGD  64
#define CLS  80
#define SPLIT 2
#define JT_PER 8   // 16 j-tiles / SPLIT

typedef __attribute__((ext_vector_type(8))) short short8;
typedef __attribute__((ext_vector_type(4))) float f32x4;
typedef __attribute__((ext_vector_type(2))) float f32x2;

// bf16 split: x ~= hi + lo, each RNE-rounded bf16.
__device__ inline void split2(float x, ushort& h, ushort& l) {
  uint u = __float_as_uint(x);
  uint rh = (u + 0x7FFFu + ((u >> 16) & 1u)) >> 16;
  h = (ushort)rh;
  float r = x - __uint_as_float(rh << 16);
  uint v = __float_as_uint(r);
  l = (ushort)((v + 0x7FFFu + ((v >> 16) & 1u)) >> 16);
}

// frag-order LDS slot for a 64-row x 32-K half-tile (16B short8 units)
__device__ inline int lslot(int r, int kc) {
  return ((r >> 4) << 6) + (kc << 4) + (r & 15);
}

// ---------------------------------------------------------------------------
// Prep 1: elementwise split fp32 -> (H,L) planes for roi (bid<256) and Wc.
// ---------------------------------------------------------------------------
__global__ __launch_bounds__(256) void split_k(
    const float* __restrict__ src0, ushort* __restrict__ H0, ushort* __restrict__ L0,
    const float* __restrict__ src1, ushort* __restrict__ H1, ushort* __restrict__ L1)
{
  const int bid = blockIdx.x;
  const float* src = bid < 256 ? src0 : src1;
  ushort* H = bid < 256 ? H0 : H1;
  ushort* L = bid < 256 ? L0 : L1;
  const int base = ((bid & 255) * 256 + threadIdx.x) * 16;
  float v[16];
  *(float4*)&v[0]  = *(const float4*)&src[base];
  *(float4*)&v[4]  = *(const float4*)&src[base + 4];
  *(float4*)&v[8]  = *(const float4*)&src[base + 8];
  *(float4*)&v[12] = *(const float4*)&src[base + 12];
  ushort hs[16], ls[16];
#pragma unroll
  for (int u = 0; u < 16; ++u) split2(v[u], hs[u], ls[u]);
  *(uint4*)&H[base]     = *(uint4*)&hs[0];
  *(uint4*)&H[base + 8] = *(uint4*)&hs[8];
  *(uint4*)&L[base]     = *(uint4*)&ls[0];
  *(uint4*)&L[base + 8] = *(uint4*)&ls[8];
}

// ---------------------------------------------------------------------------
// Prep 2: transpose + split for Wq/Wk: WT[j][k] = W[k][j] -> (H,L) planes.
// ---------------------------------------------------------------------------
__global__ __launch_bounds__(256) void splitT_k(
    const float* __restrict__ W0, const float* __restrict__ W1,
    ushort* __restrict__ H0, ushort* __restrict__ L0,
    ushort* __restrict__ H1, ushort* __restrict__ L1)
{
  const float* W = blockIdx.z ? W1 : W0;
  ushort* H = blockIdx.z ? H1 : H0;
  ushort* L = blockIdx.z ? L1 : L0;
  const int j0 = blockIdx.x * 64, k0 = blockIdx.y * 64;
  __shared__ float Tl[64][68];
  const int t = threadIdx.x, r = t >> 2, c = (t & 3) * 16;
#pragma unroll
  for (int u = 0; u < 4; ++u)
    *(float4*)&Tl[r][c + u * 4] = *(const float4*)&W[(k0 + r) * NN + j0 + c + u * 4];
  __syncthreads();
  ushort hs[16], ls[16];
#pragma unroll
  for (int u = 0; u < 16; ++u) split2(Tl[c + u][r], hs[u], ls[u]);
  const int ob = (j0 + r) * NN + k0 + c;
  *(uint4*)&H[ob]     = *(uint4*)&hs[0];
  *(uint4*)&H[ob + 8] = *(uint4*)&hs[8];
  *(uint4*)&L[ob]     = *(uint4*)&ls[0];
  *(uint4*)&L[ob + 8] = *(uint4*)&ls[8];
}

// ---------------------------------------------------------------------------
// Kernel 1 (MFMA): q/k = roi @ W^T + bias, written as split bf16 planes.
// ---------------------------------------------------------------------------
__global__ __launch_bounds__(256) void gemm_qk_m(
    const ushort* __restrict__ AH, const ushort* __restrict__ AL,
    const ushort* __restrict__ B0H, const ushort* __restrict__ B0L,
    const ushort* __restrict__ B1H, const ushort* __restrict__ B1L,
    const float* __restrict__ b0, const float* __restrict__ b1,
    ushort* __restrict__ qhp, ushort* __restrict__ qlp,
    ushort* __restrict__ khp, ushort* __restrict__ klp)
{
  const ushort* BH = blockIdx.z ? B1H : B0H;
  const ushort* BL = blockIdx.z ? B1L : B0L;
  const float* bias = blockIdx.z ? b1 : b0;
  ushort* OH = blockIdx.z ? khp : qhp;
  ushort* OL = blockIdx.z ? klp : qlp;
  const int j0 = blockIdx.x * 128, i0 = blockIdx.y * 128;
  const int t = threadIdx.x, lane = t & 63, w = t >> 6;
  const int wr = w >> 1, wc = w & 1;

  __shared__ short8 sAH[512], sAL[512], sBH[512], sBL[512];

  const int kc = t & 3, r = t >> 2;
  const int slot0 = lslot(r, kc);
  const int slot1 = slot0 + 256;

  uint4 vah0, vah1, val0, val1, vbh0, vbh1, vbl0, vbl1;
#define LOADT(kt) { \
    const int ka = (kt) * 32 + (kc << 3); \
    vah0 = *(const uint4*)&AH[(i0 + r) * NN + ka]; \
    vah1 = *(const uint4*)&AH[(i0 + r + 64) * NN + ka]; \
    val0 = *(const uint4*)&AL[(i0 + r) * NN + ka]; \
    val1 = *(const uint4*)&AL[(i0 + r + 64) * NN + ka]; \
    vbh0 = *(const uint4*)&BH[(j0 + r) * NN + ka]; \
    vbh1 = *(const uint4*)&BH[(j0 + r + 64) * NN + ka]; \
    vbl0 = *(const uint4*)&BL[(j0 + r) * NN + ka]; \
    vbl1 = *(const uint4*)&BL[(j0 + r + 64) * NN + ka]; }

  LOADT(0);
  f32x4 acc[4][4] = {};

  for (int kt = 0; kt < 32; ++kt) {
    __syncthreads();
    *(uint4*)&sAH[slot0] = vah0; *(uint4*)&sAH[slot1] = vah1;
    *(uint4*)&sAL[slot0] = val0; *(uint4*)&sAL[slot1] = val1;
    *(uint4*)&sBH[slot0] = vbh0; *(uint4*)&sBH[slot1] = vbh1;
    *(uint4*)&sBL[slot0] = vbl0; *(uint4*)&sBL[slot1] = vbl1;
    __syncthreads();
    if (kt + 1 < 32) LOADT(kt + 1);
    short8 ah[4], al[4], bh[4], bl[4];
#pragma unroll
    for (int f = 0; f < 4; ++f) {
      ah[f] = sAH[(wr * 4 + f) * 64 + lane];
      al[f] = sAL[(wr * 4 + f) * 64 + lane];
      bh[f] = sBH[(wc * 4 + f) * 64 + lane];
      bl[f] = sBL[(wc * 4 + f) * 64 + lane];
    }
#pragma unroll
    for (int fm = 0; fm < 4; ++fm)
#pragma unroll
      for (int fn = 0; fn < 4; ++fn) {
        acc[fm][fn] = __builtin_amdgcn_mfma_f32_16x16x32_bf16(ah[fm], bh[fn], acc[fm][fn], 0, 0, 0);
        acc[fm][fn] = __builtin_amdgcn_mfma_f32_16x16x32_bf16(ah[fm], bl[fn], acc[fm][fn], 0, 0, 0);
        acc[fm][fn] = __builtin_amdgcn_mfma_f32_16x16x32_bf16(al[fm], bh[fn], acc[fm][fn], 0, 0, 0);
      }
  }
#undef LOADT

  const int crow = (lane >> 4) * 4, ccol = lane & 15;
#pragma unroll
  for (int fm = 0; fm < 4; ++fm) {
    const int row = i0 + wr * 64 + fm * 16 + crow;
#pragma unroll
    for (int fn = 0; fn < 4; ++fn) {
      const int col = j0 + wc * 64 + fn * 16 + ccol;
      const float bb = bias[col];
#pragma unroll
      for (int e = 0; e < 4; ++e) {
        float v = acc[fm][fn][e] + bb;
        ushort hh, ll; split2(v, hh, ll);
        OH[(size_t)(row + e) * NN + col] = hh;
        OL[(size_t)(row + e) * NN + col] = ll;
      }
    }
  }
}

// ---------------------------------------------------------------------------
// Kernel 2 (MFMA): RWT[g][kk][j] = sum_d Wc[g][kk][d] * roi[j][d]  (NT)
// ---------------------------------------------------------------------------
__global__ __launch_bounds__(256) void gemm_rwt_m(
    const ushort* __restrict__ AH, const ushort* __restrict__ AL,   // Wc planes
    const ushort* __restrict__ BH, const ushort* __restrict__ BL,   // roi planes
    ushort* __restrict__ rwhp, ushort* __restrict__ rwlp)
{
  const int g = blockIdx.y, j0 = blockIdx.x * 128;
  const int t = threadIdx.x, lane = t & 63, w = t >> 6;
  const int wm = w >> 1, wn = w & 1;
  const ushort* AgH = AH + (size_t)g * DGD * NN;
  const ushort* AgL = AL + (size_t)g * DGD * NN;

  __shared__ short8 sAH[256], sAL[256], sBH[512], sBL[512];

  const int kc = t & 3, r = t >> 2;
  const int slot0 = lslot(r, kc);
  const int slot1 = slot0 + 256;

  uint4 vah, val, vbh0, vbh1, vbl0, vbl1;
#define LOADT(kt) { \
    const int ka = (kt) * 32 + (kc << 3); \
    vah  = *(const uint4*)&AgH[r * NN + ka]; \
    val  = *(const uint4*)&AgL[r * NN + ka]; \
    vbh0 = *(const uint4*)&BH[(j0 + r) * NN + ka]; \
    vbh1 = *(const uint4*)&BH[(j0 + r + 64) * NN + ka]; \
    vbl0 = *(const uint4*)&BL[(j0 + r) * NN + ka]; \
    vbl1 = *(const uint4*)&BL[(j0 + r + 64) * NN + ka]; }

  LOADT(0);
  f32x4 acc[2][4] = {};

  for (int kt = 0; kt < 32; ++kt) {
    __syncthreads();
    *(uint4*)&sAH[slot0] = vah;  *(uint4*)&sAL[slot0] = val;
    *(uint4*)&sBH[slot0] = vbh0; *(uint4*)&sBH[slot1] = vbh1;
    *(uint4*)&sBL[slot0] = vbl0; *(uint4*)&sBL[slot1] = vbl1;
    __syncthreads();
    if (kt + 1 < 32) LOADT(kt + 1);
    short8 ah[2], al[2], bh[4], bl[4];
#pragma unroll
    for (int f = 0; f < 2; ++f) {
      ah[f] = sAH[(wm * 2 + f) * 64 + lane];
      al[f] = sAL[(wm * 2 + f) * 64 + lane];
    }
#pragma unroll
    for (int f = 0; f < 4; ++f) {
      bh[f] = sBH[(wn * 4 + f) * 64 + lane];
      bl[f] = sBL[(wn * 4 + f) * 64 + lane];
    }
#pragma unroll
    for (int fm = 0; fm < 2; ++fm)
#pragma unroll
      for (int fn = 0; fn < 4; ++fn) {
        acc[fm][fn] = __builtin_amdgcn_mfma_f32_16x16x32_bf16(ah[fm], bh[fn], acc[fm][fn], 0, 0, 0);
        acc[fm][fn] = __builtin_amdgcn_mfma_f32_16x16x32_bf16(ah[fm], bl[fn], acc[fm][fn], 0, 0, 0);
        acc[fm][fn] = __builtin_amdgcn_mfma_f32_16x16x32_bf16(al[fm], bh[fn], acc[fm][fn], 0, 0, 0);
      }
  }
#undef LOADT

  const int crow = (lane >> 4) * 4, ccol = lane & 15;
#pragma unroll
  for (int fm = 0; fm < 2; ++fm) {
    const int row = wm * 32 + fm * 16 + crow;   // kk
#pragma unroll
    for (int fn = 0; fn < 4; ++fn) {
      const int col = j0 + wn * 64 + fn * 16 + ccol;   // j
#pragma unroll
      for (int e = 0; e < 4; ++e) {
        ushort hh, ll; split2(acc[fm][fn][e], hh, ll);
        rwhp[((size_t)g * DGD + row + e) * NN + col] = hh;
        rwlp[((size_t)g * DGD + row + e) * NN + col] = ll;
      }
    }
  }
}

// ---------------------------------------------------------------------------
// Kernel 3: paff = log(max(relu(emb@W_pos + b_pos), 1e-6))
// 4 j per thread, float4 W reads (was scalar ds_read-bound), f32x2 packed FMA.
// launch_bounds(256,1): allow full VGPR budget (R5's 4j version spilled).
// ---------------------------------------------------------------------------
__global__ __launch_bounds__(256, 1) void posaff_k(
    const float* __restrict__ bbox, const float* __restrict__ Wp,
    const float* __restrict__ bp, float* __restrict__ paff)
{
  const int i = blockIdx.x;
  const int t = threadIdx.x;
  const int j0 = t * 4;

  __shared__ float WpS[1024];
  __shared__ float bpS[16];
  for (int u = t; u < 1024; u += 256) WpS[u] = Wp[u];
  if (t < 16) bpS[t] = bp[t];
  __syncthreads();

  const float xi0 = bbox[i*4+0], yi0 = bbox[i*4+1], xi1 = bbox[i*4+2], yi1 = bbox[i*4+3];
  const float wi = xi1 - xi0 + 1.0f, hi = yi1 - yi0 + 1.0f;
  const float cxi = 0.5f*(xi0+xi1), cyi = 0.5f*(yi0+yi1);

  float pos[4][4];
#pragma unroll
  for (int jj = 0; jj < 4; ++jj) {
    float4 bj = *(const float4*)&bbox[(j0 + jj) * 4];
    const float wj = bj.z - bj.x + 1.0f, hj = bj.w - bj.y + 1.0f;
    const float cxj = 0.5f*(bj.x+bj.z), cyj = 0.5f*(bj.y+bj.w);
    pos[0][jj] = __logf(fmaxf(fabsf((cxi - cxj) / wi), 1e-3f));
    pos[1][jj] = __logf(fmaxf(fabsf((cyi - cyj) / hi), 1e-3f));
    pos[2][jj] = __logf(fmaxf(fabsf(wi / wj), 1e-3f));
    pos[3][jj] = __logf(fmaxf(fabsf(hi / hj), 1e-3f));
  }

  const float invdim[8] = {1.0f, 0.42169650342858224f, 0.17782794100389228f,
      0.07498942093324558f, 0.03162277660168379f, 0.01333521432163324f,
      0.005623413251903491f, 0.0023713737056616554f};

  f32x2 acc[16][2];
#pragma unroll
  for (int g = 0; g < 16; ++g) {
    acc[g][0] = (f32x2){bpS[g], bpS[g]};
    acc[g][1] = (f32x2){bpS[g], bpS[g]};
  }

#pragma unroll
  for (int c = 0; c < 4; ++c) {
#pragma unroll
    for (int rr = 0; rr < 8; ++rr) {
      float sn[4], cn[4];
#pragma unroll
      for (int jj = 0; jj < 4; ++jj)
        __sincosf(pos[c][jj] * invdim[rr], &sn[jj], &cn[jj]);
      const f32x2 sn0 = {sn[0], sn[1]}, sn1 = {sn[2], sn[3]};
      const f32x2 cn0 = {cn[0], cn[1]}, cn1 = {cn[2], cn[3]};
      const float* w1 = &WpS[(c * 16 + rr) * 16];
      const float* w2 = w1 + 128;   // (c*16+8+rr)*16
#pragma unroll
      for (int g4 = 0; g4 < 4; ++g4) {
        float4 a1 = *(const float4*)&w1[g4 * 4];
        float4 a2 = *(const float4*)&w2[g4 * 4];
        const float* a1s = (const float*)&a1;
        const float* a2s = (const float*)&a2;
#pragma unroll
        for (int gg = 0; gg < 4; ++gg) {
          const int g = g4 * 4 + gg;
          const f32x2 A1 = {a1s[gg], a1s[gg]};
          const f32x2 A2 = {a2s[gg], a2s[gg]};
          acc[g][0] = __builtin_elementwise_fma(sn0, A1,
                        __builtin_elementwise_fma(cn0, A2, acc[g][0]));
          acc[g][1] = __builtin_elementwise_fma(sn1, A1,
                        __builtin_elementwise_fma(cn1, A2, acc[g][1]));
        }
      }
    }
  }
#pragma unroll
  for (int g = 0; g < 16; ++g) {
    float4 ov;
    ov.x = __logf(fmaxf(acc[g][0][0], 1e-6f));
    ov.y = __logf(fmaxf(acc[g][0][1], 1e-6f));
    ov.z = __logf(fmaxf(acc[g][1][0], 1e-6f));
    ov.w = __logf(fmaxf(acc[g][1][1], 1e-6f));
    *(float4*)&paff[((i * GG + g) << 10) + j0] = ov;
  }
}

// ---------------------------------------------------------------------------
// Kernel 4 (MFMA flash): block = 64 i-rows x g, SPLIT over j.
// ---------------------------------------------------------------------------
__global__ __launch_bounds__(256) void attn_m(
    const ushort* __restrict__ qhp, const ushort* __restrict__ qlp,
    const ushort* __restrict__ khp, const ushort* __restrict__ klp,
    const ushort* __restrict__ rwhp, const ushort* __restrict__ rwlp,
    const float* __restrict__ paff,
    float* __restrict__ po, float* __restrict__ pstat)
{
  const int g  = blockIdx.y;
  const int i0 = blockIdx.x * 64;
  const int sp = blockIdx.z;
  const int t  = threadIdx.x;
  const int lane = t & 63, w = t >> 6;

  __shared__ short8 sQH[512], sQL[512], sKH[512], sKL[512], sRH[512], sRL[512];
  __shared__ float PT[4][16][68];

  const int r  = t >> 2;
  const int kc = t & 3;
  const int sl = lslot(r, kc);

  // ---- stage Q (64 x 64, 2 K-halves x 2 planes) ----
  {
    const ushort* s0 = qhp + (size_t)(i0 + r) * NN + g * DGD + kc * 8;
    const ushort* s1 = qlp + (size_t)(i0 + r) * NN + g * DGD + kc * 8;
    *(uint4*)&sQH[sl]       = *(const uint4*)&s0[0];
    *(uint4*)&sQH[sl + 256] = *(const uint4*)&s0[32];
    *(uint4*)&sQL[sl]       = *(const uint4*)&s1[0];
    *(uint4*)&sQL[sl + 256] = *(const uint4*)&s1[32];
  }
  __syncthreads();
  const short8 qf_h0 = sQH[w * 64 + lane], qf_h1 = sQH[256 + w * 64 + lane];
  const short8 qf_l0 = sQL[w * 64 + lane], qf_l1 = sQL[256 + w * 64 + lane];

  const int qr = (lane >> 4) * 4;   // row base within frag
  const int qc = lane & 15;         // col within frag

  float m[4], l[4];
  f32x4 o[4] = {};
#pragma unroll
  for (int e = 0; e < 4; ++e) { m[e] = -1e30f; l[e] = 0.f; }

#pragma unroll 1
  for (int jt = sp * JT_PER; jt < sp * JT_PER + JT_PER; ++jt) {
    const int j0 = jt * 64;
    const ushort* ks0 = khp + (size_t)(j0 + r) * NN + g * DGD + kc * 8;
    const ushort* ks1 = klp + (size_t)(j0 + r) * NN + g * DGD + kc * 8;
    uint4 kv00 = *(const uint4*)&ks0[0], kv01 = *(const uint4*)&ks0[32];
    uint4 kv10 = *(const uint4*)&ks1[0], kv11 = *(const uint4*)&ks1[32];
    const ushort* rs0 = rwhp + ((size_t)g * DGD + r) * NN + j0 + kc * 8;
    const ushort* rs1 = rwlp + ((size_t)g * DGD + r) * NN + j0 + kc * 8;
    uint4 rv00 = *(const uint4*)&rs0[0], rv01 = *(const uint4*)&rs0[32];
    uint4 rv10 = *(const uint4*)&rs1[0], rv11 = *(const uint4*)&rs1[32];
    float pf[4][4];
#pragma unroll
    for (int jf = 0; jf < 4; ++jf)
#pragma unroll
      for (int e = 0; e < 4; ++e)
        pf[jf][e] = paff[(((i0 + w * 16 + qr + e) * GG + g) << 10) + j0 + jf * 16 + qc];

    __syncthreads();   // A: prev iteration's MFMA reads done
    *(uint4*)&sKH[sl] = kv00; *(uint4*)&sKH[sl + 256] = kv01;
    *(uint4*)&sKL[sl] = kv10; *(uint4*)&sKL[sl + 256] = kv11;
    *(uint4*)&sRH[sl] = rv00; *(uint4*)&sRH[sl + 256] = rv01;
    *(uint4*)&sRL[sl] = rv10; *(uint4*)&sRL[sl + 256] = rv11;
    __syncthreads();   // B: tiles visible

    // ---- QK^T (split-3) ----
    f32x4 s4[4];
#pragma unroll
    for (int jf = 0; jf < 4; ++jf) {
      short8 bh0 = sKH[jf * 64 + lane], bh1 = sKH[256 + jf * 64 + lane];
      short8 bl0 = sKL[jf * 64 + lane], bl1 = sKL[256 + jf * 64 + lane];
      f32x4 a = {0.f, 0.f, 0.f, 0.f};
      a = __builtin_amdgcn_mfma_f32_16x16x32_bf16(qf_h0, bh0, a, 0, 0, 0);
      a = __builtin_amdgcn_mfma_f32_16x16x32_bf16(qf_h1, bh1, a, 0, 0, 0);
      a = __builtin_amdgcn_mfma_f32_16x16x32_bf16(qf_h0, bl0, a, 0, 0, 0);
      a = __builtin_amdgcn_mfma_f32_16x16x32_bf16(qf_h1, bl1, a, 0, 0, 0);
      a = __builtin_amdgcn_mfma_f32_16x16x32_bf16(qf_l0, bh0, a, 0, 0, 0);
      a = __builtin_amdgcn_mfma_f32_16x16x32_bf16(qf_l1, bh1, a, 0, 0, 0);
      s4[jf] = a;
    }

    // ---- online softmax (per row e, 16-lane groups) ----
#pragma unroll
    for (int e = 0; e < 4; ++e) {
      float v0 = fmaf(s4[0][e], 0.125f, pf[0][e]);
      float v1 = fmaf(s4[1][e], 0.125f, pf[1][e]);
      float v2 = fmaf(s4[2][e], 0.125f, pf[2][e]);
      float v3 = fmaf(s4[3][e], 0.125f, pf[3][e]);
      float tm = fmaxf(fmaxf(v0, v1), fmaxf(v2, v3));
#pragma unroll
      for (int off = 1; off < 16; off <<= 1) tm = fmaxf(tm, __shfl_xor(tm, off, 64));
      const float mn = fmaxf(m[e], tm);
      const float sc = __expf(m[e] - mn);
      v0 = __expf(v0 - mn); v1 = __expf(v1 - mn);
      v2 = __expf(v2 - mn); v3 = __expf(v3 - mn);
      float ts = (v0 + v1) + (v2 + v3);
#pragma unroll
      for (int off = 1; off < 16; off <<= 1) ts += __shfl_xor(ts, off, 64);
      l[e] = l[e] * sc + ts;
      m[e] = mn;
#pragma unroll
      for (int nf = 0; nf < 4; ++nf) o[nf][e] *= sc;
      PT[w][qr + e][ 0 + qc] = v0;
      PT[w][qr + e][16 + qc] = v1;
      PT[w][qr + e][32 + qc] = v2;
      PT[w][qr + e][48 + qc] = v3;
    }

    // ---- P frags (A-operand layout) + split ----
    short8 ph[2], pl[2];
#pragma unroll
    for (int h = 0; h < 2; ++h) {
      const float* psrc = &PT[w][lane & 15][h * 32 + (lane >> 4) * 8];
      float4 x = *(const float4*)&psrc[0];
      float4 y = *(const float4*)&psrc[4];
      float vv[8] = {x.x, x.y, x.z, x.w, y.x, y.y, y.z, y.w};
      ushort hh[8], ll[8];
#pragma unroll
      for (int u = 0; u < 8; ++u) split2(vv[u], hh[u], ll[u]);
      ph[h] = *(short8*)&hh[0];
      pl[h] = *(short8*)&ll[0];
    }

    // ---- PV (split-3) ----
#pragma unroll
    for (int nf = 0; nf < 4; ++nf) {
      short8 rh0 = sRH[nf * 64 + lane], rh1 = sRH[256 + nf * 64 + lane];
      short8 rl0 = sRL[nf * 64 + lane], rl1 = sRL[256 + nf * 64 + lane];
      f32x4 a = o[nf];
      a = __builtin_amdgcn_mfma_f32_16x16x32_bf16(ph[0], rh0, a, 0, 0, 0);
      a = __builtin_amdgcn_mfma_f32_16x16x32_bf16(ph[1], rh1, a, 0, 0, 0);
      a = __builtin_amdgcn_mfma_f32_16x16x32_bf16(ph[0], rl0, a, 0, 0, 0);
      a = __builtin_amdgcn_mfma_f32_16x16x32_bf16(ph[1], rl1, a, 0, 0, 0);
      a = __builtin_amdgcn_mfma_f32_16x16x32_bf16(pl[0], rh0, a, 0, 0, 0);
      a = __builtin_amdgcn_mfma_f32_16x16x32_bf16(pl[1], rh1, a, 0, 0, 0);
      o[nf] = a;
    }
  }

  // ---- epilogue: unnormalized partials + stats ----
  const size_t idx = ((size_t)blockIdx.x * GG + g) * SPLIT + sp;
  float* pot = po + idx * 4096;
#pragma unroll
  for (int nf = 0; nf < 4; ++nf)
#pragma unroll
    for (int e = 0; e < 4; ++e)
      pot[(w * 16 + qr + e) * 64 + nf * 16 + qc] = o[nf][e];
  if (qc == 0) {
#pragma unroll
    for (int e = 0; e < 4; ++e) {
      const int row = w * 16 + qr + e;
      pstat[(idx * 64 + row) * 2]     = m[e];
      pstat[(idx * 64 + row) * 2 + 1] = l[e];
    }
  }
}

// ---------------------------------------------------------------------------
// Kernel 4b: combine split partials -> res (+ residual + bias)
// ---------------------------------------------------------------------------
__global__ __launch_bounds__(256) void combine_k(
    const float* __restrict__ po, const float* __restrict__ pstat,
    const float* __restrict__ roi, const float* __restrict__ bconv,
    float* __restrict__ res)
{
  const int it = blockIdx.x, g = blockIdx.y;
  const int t = threadIdx.x;
  const int row = t >> 2, c0 = (t & 3) * 16;
  const size_t base = ((size_t)it * GG + g) * SPLIT;

  float ms[SPLIT], ls[SPLIT];
#pragma unroll
  for (int s = 0; s < SPLIT; ++s) {
    float2 st = *(const float2*)&pstat[((base + s) * 64 + row) * 2];
    ms[s] = st.x; ls[s] = st.y;
  }
  float M = ms[0];
#pragma unroll
  for (int s = 1; s < SPLIT; ++s) M = fmaxf(M, ms[s]);
  float wgt[SPLIT], L = 0.f;
#pragma unroll
  for (int s = 0; s < SPLIT; ++s) { wgt[s] = __expf(ms[s] - M); L = fmaf(ls[s], wgt[s], L); }
  const float rL = 1.0f / L;

  const int grow = it * 64 + row;
  const int f0   = g * DGD + c0;
#pragma unroll
  for (int c = 0; c < 4; ++c) {
    float4 acc = {0.f, 0.f, 0.f, 0.f};
#pragma unroll
    for (int s = 0; s < SPLIT; ++s) {
      float4 v = *(const float4*)&po[(base + s) * 4096 + row * 64 + c0 + c * 4];
      acc.x = fmaf(v.x, wgt[s], acc.x);
      acc.y = fmaf(v.y, wgt[s], acc.y);
      acc.z = fmaf(v.z, wgt[s], acc.z);
      acc.w = fmaf(v.w, wgt[s], acc.w);
    }
    float4 r4 = *(const float4*)&roi[grow * NN + f0 + c * 4];
    float4 b4 = *(const float4*)&bconv[f0 + c * 4];
    float4 ov;
    ov.x = r4.x + b4.x + acc.x * rL;
    ov.y = r4.y + b4.y + acc.y * rL;
    ov.z = r4.z + b4.z + acc.z * rL;
    ov.w = r4.w + b4.w + acc.w * rL;
    *(float4*)&res[grow * NN + f0 + c * 4] = ov;
  }
}

// ---------------------------------------------------------------------------
// Kernel 5a: partial column sums of res
// ---------------------------------------------------------------------------
__global__ __launch_bounds__(256) void colsum_partial_k(
    const float* __restrict__ res, float* __restrict__ part)
{
  const int d  = blockIdx.x * 256 + threadIdx.x;
  const int r0 = blockIdx.y * 128;
  float s0 = 0.f, s1 = 0.f, s2 = 0.f, s3 = 0.f;
  for (int i = 0; i < 128; i += 4) {
    s0 += res[(r0 + i    ) * NN + d];
    s1 += res[(r0 + i + 1) * NN + d];
    s2 += res[(r0 + i + 2) * NN + d];
    s3 += res[(r0 + i + 3) * NN + d];
  }
  part[blockIdx.y * NN + d] = (s0 + s1) + (s2 + s3);
}

// ---------------------------------------------------------------------------
// Kernel 5b: reduce partials, logits = colsum@W_ro + b_ro, sigmoid.
// 640 threads: t = s*80+c; 8-way d-split per class, LDS reduce.
// ---------------------------------------------------------------------------
__global__ __launch_bounds__(640) void final_k(
    const float* __restrict__ part, const float* __restrict__ W_ro,
    const float* __restrict__ b_ro, float* __restrict__ out)
{
  __shared__ float cs[1024];
  __shared__ float red[8][CLS];
  const int t = threadIdx.x;

  for (int u = t; u < 1024; u += 640) {
    float s = 0.f;
#pragma unroll
    for (int p = 0; p < 8; ++p) s += part[p * NN + u];
    cs[u] = s;
  }
  __syncthreads();

  {
    const int c = t % CLS, s = t / CLS;   // s in 0..7
    float acc = 0.f;
    const int d0 = s * 128;
#pragma unroll 8
    for (int d = d0; d < d0 + 128; ++d)
      acc = fmaf(cs[d], W_ro[d * CLS + c], acc);
    red[s][c] = acc;
  }
  __syncthreads();

  if (t < CLS) {
    float lg = b_ro[t];
#pragma unroll
    for (int s = 0; s < 8; ++s) lg += red[s][t];
    out[t] = 1.0f / (1.0f + __expf(-lg));
  }
}

// ---------------------------------------------------------------------------
extern "C" void kernel_launch(void* const* d_in, const int* in_sizes, int n_in,
                              void* d_out, int out_size, void* d_ws, size_t ws_size,
                              hipStream_t stream) {
  const float* bbox  = (const float*)d_in[0];
  const float* roi   = (const float*)d_in[1];
  const float* W_pos = (const float*)d_in[2];
  const float* b_pos = (const float*)d_in[3];
  const float* Wq    = (const float*)d_in[4];
  const float* bq    = (const float*)d_in[5];
  const float* Wk    = (const float*)d_in[6];
  const float* bk    = (const float*)d_in[7];
  const float* Wc    = (const float*)d_in[8];
  const float* bcv   = (const float*)d_in[9];
  const float* W_ro  = (const float*)d_in[10];
  const float* b_ro  = (const float*)d_in[11];

  float* ws = (float*)d_ws;
  // region A: paff lives posaff->attn
  float* paff = ws;                                     // 16M floats
  // region B: prep planes (dead after the two GEMMs)
  ushort* roiH = (ushort*)(ws + (16 << 20));
  ushort* roiL = (ushort*)(ws + (16 << 20) + (1 << 19));
  ushort* WqTH = (ushort*)(ws + (17 << 20));
  ushort* WqTL = (ushort*)(ws + (17 << 20) + (1 << 19));
  ushort* WkTH = (ushort*)(ws + (18 << 20));
  ushort* WkTL = (ushort*)(ws + (18 << 20) + (1 << 19));
  ushort* WcH  = (ushort*)(ws + (19 << 20));
  ushort* WcL  = (ushort*)(ws + (19 << 20) + (1 << 19));
  // region B reuse (attn outputs, written after preps are dead)
  float* po    = ws + (16 << 20);                       // 2M floats
  float* pstat = ws + (18 << 20);                       // 64K floats
  float* part  = ws + (18 << 20) + (1 << 18);           // 8K floats
  float* res   = ws + (19 << 20);                       // 1M floats
  // region C: split q/k/RWT planes (live gemm->attn)
  ushort* qHp  = (ushort*)(ws + (20 << 20));
  ushort* qLp  = (ushort*)(ws + (20 << 20) + (1 << 19));
  ushort* kHp  = (ushort*)(ws + (21 << 20));
  ushort* kLp  = (ushort*)(ws + (21 << 20) + (1 << 19));
  ushort* rwHp = (ushort*)(ws + (22 << 20));
  ushort* rwLp = (ushort*)(ws + (22 << 20) + (1 << 19));

  split_k<<<512, 256, 0, stream>>>(roi, roiH, roiL, Wc, WcH, WcL);
  splitT_k<<<dim3(16, 16, 2), 256, 0, stream>>>(Wq, Wk, WqTH, WqTL, WkTH, WkTL);

  gemm_qk_m<<<dim3(8, 8, 2), 256, 0, stream>>>(roiH, roiL, WqTH, WqTL, WkTH, WkTL,
                                               bq, bk, qHp, qLp, kHp, kLp);
  gemm_rwt_m<<<dim3(8, 16), 256, 0, stream>>>(WcH, WcL, roiH, roiL, rwHp, rwLp);

  posaff_k<<<1024, 256, 0, stream>>>(bbox, W_pos, b_pos, paff);
  attn_m<<<dim3(16, 16, SPLIT), 256, 0, stream>>>(qHp, qLp, kHp, kLp, rwHp, rwLp,
                                                  paff, po, pstat);
  combine_k<<<dim3(16, 16), 256, 0, stream>>>(po, pstat, roi, bcv, res);
  colsum_partial_k<<<dim3(4, 8), 256, 0, stream>>>(res, part);
  final_k<<<1, 640, 0, stream>>>(part, W_ro, b_ro, (float*)d_out);
}